// Round 25
// baseline (634.057 us; speedup 1.0000x reference)
//
#include <hip/hip_runtime.h>

#define NPTS 8192
#define NB 2

typedef __attribute__((ext_vector_type(8))) short short8v;   // 8 bf16 (4 VGPRs)
typedef __attribute__((ext_vector_type(4))) float f32x4;

__device__ __forceinline__ float lrelu(float x) { return x > 0.f ? x : 0.2f * x; }
__device__ __forceinline__ float4 lrelu4(float4 a) {
    return make_float4(lrelu(a.x), lrelu(a.y), lrelu(a.z), lrelu(a.w));
}
__device__ __forceinline__ float4 fmax4(float4 a, float4 b) {
    return make_float4(fmaxf(a.x, b.x), fmaxf(a.y, b.y), fmaxf(a.z, b.z), fmaxf(a.w, b.w));
}
__device__ __forceinline__ float4 add4(float4 a, float4 b) {
    return make_float4(a.x + b.x, a.y + b.y, a.z + b.z, a.w + b.w);
}
__device__ __forceinline__ unsigned short f2bf(float f) {     // RNE bf16
    unsigned int u = __float_as_uint(f);
    return (unsigned short)((u + 0x7FFFu + ((u >> 16) & 1u)) >> 16);
}
__device__ __forceinline__ float bf2f(unsigned short h) {
    return __uint_as_float(((unsigned int)h) << 16);
}

// ---------------- prep: transpose layer-2 weights into ws (WbT[c][o]) ----------------
__global__ void k_transpose_w(const float* __restrict__ Wb0, const float* __restrict__ Wb1,
                              float* __restrict__ out) {
    int t = blockIdx.x * 256 + threadIdx.x;
    if (t < 16384)      out[t] = Wb0[(t & 127) * 128 + (t >> 7)];
    else if (t < 32768) { int i = t - 16384; out[t] = Wb1[(i & 127) * 128 + (i >> 7)]; }
}

// 3-way bf16 split of a float4, packed into 2 uints per level
__device__ __forceinline__ void split3(float4 v, unsigned int* hp, unsigned int* mp,
                                       unsigned int* lp) {
    float c[4] = {v.x, v.y, v.z, v.w};
    unsigned short h[4], m[4], l[4];
    #pragma unroll
    for (int i = 0; i < 4; ++i) {
        h[i] = f2bf(c[i]);
        float r1 = c[i] - bf2f(h[i]);
        m[i] = f2bf(r1);
        float r2 = r1 - bf2f(m[i]);
        l[i] = f2bf(r2);
    }
    hp[0] = (unsigned int)h[0] | ((unsigned int)h[1] << 16);
    hp[1] = (unsigned int)h[2] | ((unsigned int)h[3] << 16);
    mp[0] = (unsigned int)m[0] | ((unsigned int)m[1] << 16);
    mp[1] = (unsigned int)m[2] | ((unsigned int)m[3] << 16);
    lp[0] = (unsigned int)l[0] | ((unsigned int)l[1] << 16);
    lp[1] = (unsigned int)l[2] | ((unsigned int)l[3] << 16);
}

// ---------------- conv_in: feature -> x0 fp32 + sq0 + bf16 h/m/l split ----------------
__global__ void k_conv_in(const float* __restrict__ f, const float* __restrict__ W,
                          const float* __restrict__ bias, float* __restrict__ out,
                          float* __restrict__ sq, unsigned short* __restrict__ xh,
                          unsigned short* __restrict__ xm, unsigned short* __restrict__ xl) {
    int gid = blockIdx.x * blockDim.x + threadIdx.x;   // over B*N
    int b = gid >> 13, n = gid & (NPTS - 1);
    const float* fb = f + ((size_t)b << 20) + n;       // b*128*8192
    float acc[32];
    #pragma unroll
    for (int o = 0; o < 32; ++o) acc[o] = bias[o];
    #pragma unroll 4
    for (int c = 0; c < 128; ++c) {
        float xc = fb[(size_t)c * NPTS];               // coalesced across lanes
        #pragma unroll
        for (int o = 0; o < 32; ++o) acc[o] += xc * W[o * 128 + c];  // uniform -> s_load
    }
    float s = 0.f;
    float4* op = (float4*)(out + (size_t)gid * 32);
    unsigned int* hrow = (unsigned int*)(xh + (size_t)gid * 32);
    unsigned int* mrow = (unsigned int*)(xm + (size_t)gid * 32);
    unsigned int* lrow = (unsigned int*)(xl + (size_t)gid * 32);
    #pragma unroll
    for (int o4 = 0; o4 < 8; ++o4) {
        float4 v = make_float4(lrelu(acc[o4 * 4]), lrelu(acc[o4 * 4 + 1]),
                               lrelu(acc[o4 * 4 + 2]), lrelu(acc[o4 * 4 + 3]));
        s += v.x * v.x + v.y * v.y + v.z * v.z + v.w * v.w;
        op[o4] = v;
        unsigned int hp[2], mp[2], lp[2];
        split3(v, hp, mp, lp);
        *(uint2*)(hrow + o4 * 2) = make_uint2(hp[0], hp[1]);
        *(uint2*)(mrow + o4 * 2) = make_uint2(mp[0], mp[1]);
        *(uint2*)(lrow + o4 * 2) = make_uint2(lp[0], lp[1]);
    }
    sq[gid] = s;
}

// ---------------- premix: A = x @ Wa1^T ; Bm = x @ (Wa2-Wa1)^T + ba ----------------
// (256,2): 128-VGPR budget so xv[8]+acc[32] stay in registers (R19 fix).
__global__ __launch_bounds__(256, 2) void k_premix(const float* __restrict__ x,
                                                   const float* __restrict__ Wa,
                                                   const float* __restrict__ ba,
                                                   float* __restrict__ A,
                                                   float* __restrict__ Bm) {
    int tid = threadIdx.x;
    int q = tid >> 6;                       // quarter (wave-uniform)
    int p = blockIdx.x * 64 + (tid & 63);   // point over NB*NPTS
    float4 xv[8];
    {
        const float4* xr = (const float4*)(x + (size_t)p * 32);
        #pragma unroll
        for (int u = 0; u < 8; ++u) xv[u] = xr[u];
    }
    const float* W0 = Wa + q * 32 * 64;     // rows q*32..q*32+31
    float acc[32];
    #pragma unroll
    for (int o = 0; o < 32; ++o) acc[o] = 0.f;
    #pragma unroll 2
    for (int c4 = 0; c4 < 8; ++c4) {
        float4 v = xv[c4];
        #pragma unroll
        for (int o = 0; o < 32; ++o) {
            const float* w = W0 + o * 64 + c4 * 4;   // uniform -> s_load
            acc[o] += v.x * w[0] + v.y * w[1] + v.z * w[2] + v.w * w[3];
        }
    }
    {
        float4* op = (float4*)(A + (size_t)p * 128 + q * 32);
        #pragma unroll
        for (int o4 = 0; o4 < 8; ++o4)
            op[o4] = make_float4(acc[o4 * 4], acc[o4 * 4 + 1], acc[o4 * 4 + 2], acc[o4 * 4 + 3]);
    }
    #pragma unroll
    for (int o = 0; o < 32; ++o) acc[o] = ba[q * 32 + o];
    #pragma unroll 2
    for (int c4 = 0; c4 < 8; ++c4) {
        float4 v = xv[c4];
        #pragma unroll
        for (int o = 0; o < 32; ++o) {
            const float* w1 = W0 + o * 64 + c4 * 4;
            const float* w2 = w1 + 32;
            acc[o] += v.x * (w2[0] - w1[0]) + v.y * (w2[1] - w1[1]) +
                      v.z * (w2[2] - w1[2]) + v.w * (w2[3] - w1[3]);
        }
    }
    {
        float4* op = (float4*)(Bm + (size_t)p * 128 + q * 32);
        #pragma unroll
        for (int o4 = 0; o4 < 8; ++o4)
            op[o4] = make_float4(acc[o4 * 4], acc[o4 * 4 + 1], acc[o4 * 4 + 2], acc[o4 * 4 + 3]);
    }
}

// ---------------- kNN via MFMA Gram, BARRIER-FREE, B double-buffered + sq staged ----------------
// R24 diagnosis: K=12 and K=4 both 149us -> chunk-serial latency (B VMEM -> MFMA ->
// select; in-loop sq s_loads) dominates, not the K-chains. Fix: prefetch next
// chunk's B frags before this chunk's MFMA; stage sq[16] into per-wave LDS strip
// at chunk top (VMEM latency covered by MFMA; selection reads are LDS broadcasts).
template <int K, int JS, int C>
__global__ __launch_bounds__(128, 2) void k_knn_mfma(const unsigned short* __restrict__ xh,
                                                     const unsigned short* __restrict__ xm,
                                                     const unsigned short* __restrict__ xl,
                                                     const float* __restrict__ sqg,
                                                     float* __restrict__ cand_d,
                                                     int* __restrict__ cand_i) {
    constexpr int IT = 128;                  // i-tile
    constexpr int JR = NPTS / JS;            // 512 for JS=16
    constexpr int NCH = JR / 16;             // chunks of 16 j
    constexpr int BPB = (NPTS / IT) * JS;    // blocks per batch
    constexpr int DS = 17;                   // Dl row stride (reads 2-way free)

    __shared__ float Dl[IT * DS];
    __shared__ float SQl[2][16];             // per-wave staged sq for current chunk
    __shared__ float bufd[C * IT];           // transposed append buffer (conflict-free)
    __shared__ int   bufj[C * IT];

    int tid = threadIdx.x;
    int bid = blockIdx.x;
    int b = bid / BPB;
    int r0b = bid - b * BPB;
    int itile = r0b / JS;
    int jseg = r0b - itile * JS;

    const unsigned short* xhb = xh + ((size_t)b * NPTS) * 32;
    const unsigned short* xmb = xm + ((size_t)b * NPTS) * 32;
    const unsigned short* xlb = xl + ((size_t)b * NPTS) * 32;
    const float* sqb = sqg + (size_t)b * NPTS;

    int lane = tid & 63;
    int w = tid >> 6;          // wave 0..1 -> i rows [w*64, w*64+64)
    int g = lane >> 4;         // k-group: k = g*8 + e
    int r15 = lane & 15;

    // A fragments hoisted and pinned
    short8v ah[4], am[4], al[4];
    #pragma unroll
    for (int t = 0; t < 4; ++t) {
        size_t ii = (size_t)(itile * IT + w * 64 + t * 16 + r15);
        ah[t] = *(const short8v*)(xhb + ii * 32 + g * 8);
        am[t] = *(const short8v*)(xmb + ii * 32 + g * 8);
        al[t] = *(const short8v*)(xlb + ii * 32 + g * 8);
    }
    #pragma unroll
    for (int t = 0; t < 4; ++t) {
        asm volatile("" : "+v"(ah[t]));
        asm volatile("" : "+v"(am[t]));
        asm volatile("" : "+v"(al[t]));
    }

    float bd[K]; int bi[K];                  // sorted ascending, registers
    #pragma unroll
    for (int r = 0; r < K; ++r) { bd[r] = 1e30f; bi[r] = 0; }
    float thr = 1e30f;
    int cnt = 0;

    auto flush = [&]() {
        #pragma unroll
        for (int u = 0; u < C; ++u) {
            float dv = bufd[u * IT + tid];
            int jv = bufj[u * IT + tid];
            float dd = (u < cnt) ? dv : 1e30f;   // 1e30 never inserts (strict <)
            int ji = jv;
            #pragma unroll
            for (int r = 0; r < K; ++r) {
                bool c = dd < bd[r];
                float tf = bd[r]; int ti = bi[r];
                bd[r] = c ? dd : bd[r]; bi[r] = c ? ji : bi[r];
                dd = c ? tf : dd;       ji = c ? ti : ji;
            }
        }
        cnt = 0; thr = bd[K - 1];
    };

#define LOADB_(J, BH, BM, BL)                                                  \
    do {                                                                       \
        size_t ja_ = (size_t)(J) + r15;                                        \
        BH = *(const short8v*)(xhb + ja_ * 32 + g * 8);                        \
        BM = *(const short8v*)(xmb + ja_ * 32 + g * 8);                        \
        BL = *(const short8v*)(xlb + ja_ * 32 + g * 8);                        \
    } while (0)

#define SQSTAGE_(J0)                                                           \
    do {                                                                       \
        if (g == 0) SQl[w][r15] = sqb[(J0) + r15];                             \
    } while (0)

#define MFMA_(BH, BM, BL)                                                      \
    do {                                                                       \
        _Pragma("unroll")                                                      \
        for (int t = 0; t < 4; ++t) {                                          \
            f32x4 acc = {0.f, 0.f, 0.f, 0.f};                                  \
            acc = __builtin_amdgcn_mfma_f32_16x16x32_bf16(am[t], BM, acc, 0, 0, 0); \
            acc = __builtin_amdgcn_mfma_f32_16x16x32_bf16(ah[t], BL, acc, 0, 0, 0); \
            acc = __builtin_amdgcn_mfma_f32_16x16x32_bf16(al[t], BH, acc, 0, 0, 0); \
            acc = __builtin_amdgcn_mfma_f32_16x16x32_bf16(ah[t], BM, acc, 0, 0, 0); \
            acc = __builtin_amdgcn_mfma_f32_16x16x32_bf16(am[t], BH, acc, 0, 0, 0); \
            acc = __builtin_amdgcn_mfma_f32_16x16x32_bf16(ah[t], BH, acc, 0, 0, 0); \
            int il_ = w * 64 + t * 16 + g * 4;                                 \
            Dl[(il_ + 0) * DS + r15] = acc[0];                                 \
            Dl[(il_ + 1) * DS + r15] = acc[1];                                 \
            Dl[(il_ + 2) * DS + r15] = acc[2];                                 \
            Dl[(il_ + 3) * DS + r15] = acc[3];                                 \
        }                                                                      \
    } while (0)

#define SELECT_(J0)                                                            \
    do {                                                                       \
        _Pragma("unroll 1")                                                    \
        for (int jq = 0; jq < 16; jq += 4) {                                   \
            float v0 = Dl[tid * DS + jq + 0];                                  \
            float v1 = Dl[tid * DS + jq + 1];                                  \
            float v2 = Dl[tid * DS + jq + 2];                                  \
            float v3 = Dl[tid * DS + jq + 3];                                  \
            float s0 = SQl[w][jq + 0];                                         \
            float s1 = SQl[w][jq + 1];                                         \
            float s2 = SQl[w][jq + 2];                                         \
            float s3 = SQl[w][jq + 3];                                         \
            int j_ = (J0) + jq;                                                \
            float d0 = s0 - 2.f * v0;                                          \
            float d1 = s1 - 2.f * v1;                                          \
            float d2 = s2 - 2.f * v2;                                          \
            float d3 = s3 - 2.f * v3;                                          \
            if (d0 < thr) { bufd[cnt * IT + tid] = d0; bufj[cnt * IT + tid] = j_ + 0; cnt++; } \
            if (d1 < thr) { bufd[cnt * IT + tid] = d1; bufj[cnt * IT + tid] = j_ + 1; cnt++; } \
            if (d2 < thr) { bufd[cnt * IT + tid] = d2; bufj[cnt * IT + tid] = j_ + 2; cnt++; } \
            if (d3 < thr) { bufd[cnt * IT + tid] = d3; bufj[cnt * IT + tid] = j_ + 3; cnt++; } \
            if (__any(cnt >= C - 3)) flush();                                  \
        }                                                                      \
    } while (0)

    int jbase = jseg * JR;
    short8v bhA, bmA, blA, bhB, bmB, blB;
    LOADB_(jbase, bhA, bmA, blA);            // prologue: B for chunk 0
    #pragma unroll 1
    for (int ch = 0; ch < NCH; ch += 2) {
        int j0 = jbase + ch * 16;
        int j1 = j0 + 16;
        // ---- body A (chunk ch) ----
        SQSTAGE_(j0);                        // VMEM issue; covered by MFMA
        LOADB_(j1, bhB, bmB, blB);           // prefetch B for chunk ch+1
        MFMA_(bhA, bmA, blA);
        SELECT_(j0);
        // ---- body B (chunk ch+1) ----
        SQSTAGE_(j1);
        int j2 = (ch + 2 < NCH) ? j1 + 16 : jbase;   // clamp tail (harmless refetch)
        LOADB_(j2, bhA, bmA, blA);           // prefetch B for next pair
        MFMA_(bhB, bmB, blB);
        SELECT_(j1);
    }
    flush();
#undef LOADB_
#undef SQSTAGE_
#undef MFMA_
#undef SELECT_
    size_t base = ((size_t)jseg * (NB * NPTS) + (size_t)(b * NPTS) + itile * IT + tid) * K;
    #pragma unroll
    for (int r = 0; r < K; ++r) { cand_d[base + r] = bd[r]; cand_i[base + r] = bi[r]; }
}

// ---------------- merge v2: register insertion-chain with per-segment early exit ----------------
template <int K, int JS>
__global__ __launch_bounds__(128, 4) void k_knn_merge2(const float* __restrict__ cand_d,
                                                       const int* __restrict__ cand_i,
                                                       int* __restrict__ idx_out) {
    int p = blockIdx.x * 128 + threadIdx.x;   // over NB*NPTS
    float bd[K]; int bi[K];
    #pragma unroll
    for (int r = 0; r < K; ++r) { bd[r] = 1e30f; bi[r] = 0; }
    float thr = 1e30f;
    #pragma unroll 1
    for (int s = 0; s < JS; ++s) {
        size_t base = ((size_t)s * (NB * NPTS) + p) * K;
        #pragma unroll 1
        for (int r = 0; r < K; ++r) {
            float d = cand_d[base + r];
            if (!(d < thr)) break;            // sorted: rest of segment can't insert
            int j = cand_i[base + r];
            float dd = d; int ji = j;
            #pragma unroll
            for (int q = 0; q < K; ++q) {
                bool c = dd < bd[q];
                float tf = bd[q]; int ti = bi[q];
                bd[q] = c ? dd : bd[q]; bi[q] = c ? ji : bi[q];
                dd = c ? tf : dd;       ji = c ? ti : ji;
            }
            thr = bd[K - 1];
        }
    }
    int* op = idx_out + (size_t)p * K;
    #pragma unroll
    for (int r = 0; r < K; ++r) op[r] = bi[r];
}

// ---------------- EdgeConv v4: register-lean 6x8 / 4x8 output tiles ----------------
template <int K>
__global__ __launch_bounds__(256, 1)
void k_edgeconv4(const int* __restrict__ idx,
                 const float* __restrict__ A, const float* __restrict__ Bm,
                 const float* __restrict__ WbTg, const float* __restrict__ bb,
                 float* __restrict__ y) {
    constexpr int TE = (K == 12) ? 6 : 4;     // edges per thread
    constexpr int EPI = 16 * TE;              // edges per iter: 96 / 64
    constexpr int PI = EPI / K;               // points per iter: 8 / 16
    constexpr int ITERS = 64 / PI;            // 8 / 4
    constexpr int NT = 256;
    constexpr int HS = 132;                   // H1 row stride

    __shared__ __align__(16) float WbT[128 * 128];
    __shared__ __align__(16) float bb_s[128];
    __shared__ __align__(16) float H1[EPI * HS];
    __shared__ __align__(16) float Pm[(K == 12) ? 16 * 128 : 4];

    int tid = threadIdx.x;
    {
        const float4* sb = (const float4*)WbTg;
        float4* db = (float4*)WbT;
        #pragma unroll
        for (int i = 0; i < 16; ++i) db[tid + i * NT] = sb[tid + i * NT];
        if (tid < 128) bb_s[tid] = bb[tid];
    }

    int b = blockIdx.x >> 7;
    int pbase = (blockIdx.x & 127) * 64;
    const int* idxb = idx + ((size_t)b * NPTS) * K;
    const float4* A4 = (const float4*)(A + ((size_t)b * NPTS) * 128);
    const float4* B4 = (const float4*)(Bm + ((size_t)b * NPTS) * 128);
    float* yb = y + ((size_t)b * NPTS) * 128;

    int og = tid & 15;        // 16 out-groups x 8 outputs
    int eg = tid >> 4;        // 16 edge-groups x TE edges
    int ebase = eg * TE;

    for (int it = 0; it < ITERS; ++it) {
        int pt0 = pbase + it * PI;
        #pragma unroll
        for (int r = 0; r < (EPI * 32) / NT; ++r) {
            int u = tid + r * NT;
            int e = u >> 5, c4 = u & 31;
            int p = pt0 + e / K;
            int j = idxb[(size_t)p * K + (e % K)];
            float4 av = A4[(size_t)j * 32 + c4];
            float4 bv = B4[(size_t)p * 32 + c4];
            *(float4*)&H1[e * HS + 4 * c4] = lrelu4(add4(av, bv));
        }
        __syncthreads();
        float4 acc[TE][2];
        {
            float4 blo = *(const float4*)&bb_s[og * 8];
            float4 bhi = *(const float4*)&bb_s[og * 8 + 4];
            #pragma unroll
            for (int e = 0; e < TE; ++e) { acc[e][0] = blo; acc[e][1] = bhi; }
        }
        #pragma unroll 2
        for (int c4 = 0; c4 < 32; ++c4) {
            float4 hv[TE];
            #pragma unroll
            for (int e = 0; e < TE; ++e)
                hv[e] = *(const float4*)&H1[(ebase + e) * HS + 4 * c4];
            #pragma unroll
            for (int j = 0; j < 4; ++j) {
                const float* wr = &WbT[(4 * c4 + j) * 128 + og * 8];
                float4 wlo = *(const float4*)wr;
                float4 whi = *(const float4*)(wr + 4);
                #pragma unroll
                for (int e = 0; e < TE; ++e) {
                    float hc = (j == 0) ? hv[e].x : (j == 1) ? hv[e].y : (j == 2) ? hv[e].z : hv[e].w;
                    acc[e][0].x += hc * wlo.x; acc[e][0].y += hc * wlo.y;
                    acc[e][0].z += hc * wlo.z; acc[e][0].w += hc * wlo.w;
                    acc[e][1].x += hc * whi.x; acc[e][1].y += hc * whi.y;
                    acc[e][1].z += hc * whi.z; acc[e][1].w += hc * whi.w;
                }
            }
        }
        float4 mlo = lrelu4(acc[0][0]), mhi = lrelu4(acc[0][1]);
        #pragma unroll
        for (int e = 1; e < TE; ++e) {
            mlo = fmax4(mlo, lrelu4(acc[e][0]));
            mhi = fmax4(mhi, lrelu4(acc[e][1]));
        }
        if constexpr (K == 4) {
            float4* yp = (float4*)&yb[((size_t)(pt0 + eg)) * 128 + og * 8];
            yp[0] = mlo; yp[1] = mhi;
            __syncthreads();
        } else {
            *(float4*)&Pm[eg * 128 + og * 8] = mlo;
            *(float4*)&Pm[eg * 128 + og * 8 + 4] = mhi;
            __syncthreads();
            #pragma unroll
            for (int r = 0; r < 4; ++r) {
                int u = tid + r * NT;
                int p = u >> 7, o = u & 127;
                yb[((size_t)(pt0 + p)) * 128 + o] =
                    fmaxf(Pm[(2 * p) * 128 + o], Pm[(2 * p + 1) * 128 + o]);
            }
        }
    }
}

// ---------------- conv_mid: y -> x1 fp32 + sq1 + bf16 h/m/l split ----------------
__global__ void k_conv_mid(const float* __restrict__ xin, const float* __restrict__ W,
                           const float* __restrict__ bias, float* __restrict__ out,
                           float* __restrict__ sq, unsigned short* __restrict__ xh,
                           unsigned short* __restrict__ xm, unsigned short* __restrict__ xl) {
    int gid = blockIdx.x * blockDim.x + threadIdx.x;
    const float4* row = (const float4*)(xin + (size_t)gid * 128);
    float acc[32];
    #pragma unroll
    for (int o = 0; o < 32; ++o) acc[o] = bias[o];
    #pragma unroll 2
    for (int c4 = 0; c4 < 32; ++c4) {
        float4 v = row[c4];
        #pragma unroll
        for (int o = 0; o < 32; ++o) {
            const float* w = W + o * 128 + c4 * 4;   // uniform -> s_load
            acc[o] += v.x * w[0] + v.y * w[1] + v.z * w[2] + v.w * w[3];
        }
    }
    float s = 0.f;
    float4* op = (float4*)(out + (size_t)gid * 32);
    unsigned int* hrow = (unsigned int*)(xh + (size_t)gid * 32);
    unsigned int* mrow = (unsigned int*)(xm + (size_t)gid * 32);
    unsigned int* lrow = (unsigned int*)(xl + (size_t)gid * 32);
    #pragma unroll
    for (int o4 = 0; o4 < 8; ++o4) {
        float4 v = make_float4(lrelu(acc[o4 * 4]), lrelu(acc[o4 * 4 + 1]),
                               lrelu(acc[o4 * 4 + 2]), lrelu(acc[o4 * 4 + 3]));
        s += v.x * v.x + v.y * v.y + v.z * v.z + v.w * v.w;
        op[o4] = v;
        unsigned int hp[2], mp[2], lp[2];
        split3(v, hp, mp, lp);
        *(uint2*)(hrow + o4 * 2) = make_uint2(hp[0], hp[1]);
        *(uint2*)(mrow + o4 * 2) = make_uint2(mp[0], mp[1]);
        *(uint2*)(lrow + o4 * 2) = make_uint2(lp[0], lp[1]);
    }
    sq[gid] = s;
}

// ---------------- decoder: y1 [B*N,128] -> out [B*N,12] ----------------
__global__ void k_decoder(const float* __restrict__ xin,
                          const float* __restrict__ W0, const float* __restrict__ b0,
                          const float* __restrict__ W1, const float* __restrict__ b1,
                          const float* __restrict__ W2, const float* __restrict__ b2,
                          float* __restrict__ out) {
    int gid = blockIdx.x * blockDim.x + threadIdx.x;
    const float4* row = (const float4*)(xin + (size_t)gid * 128);
    float h0[6];
    #pragma unroll
    for (int o = 0; o < 6; ++o) h0[o] = b0[o];
    #pragma unroll 4
    for (int c4 = 0; c4 < 32; ++c4) {
        float4 v = row[c4];
        #pragma unroll
        for (int o = 0; o < 6; ++o) {
            const float* w = W0 + o * 128 + c4 * 4;
            h0[o] += v.x * w[0] + v.y * w[1] + v.z * w[2] + v.w * w[3];
        }
    }
    #pragma unroll
    for (int o = 0; o < 6; ++o) h0[o] = lrelu(h0[o]);
    float h1[12];
    #pragma unroll
    for (int o = 0; o < 12; ++o) {
        float a = b1[o];
        #pragma unroll
        for (int j = 0; j < 6; ++j) a += W1[o * 6 + j] * h0[j];
        h1[o] = lrelu(a);
    }
    float* op = out + (size_t)gid * 12;
    #pragma unroll
    for (int o = 0; o < 12; ++o) {
        float a = b2[o];
        #pragma unroll
        for (int j = 0; j < 12; ++j) a += W2[o * 12 + j] * h1[j];
        op[o] = a;
    }
}

extern "C" void kernel_launch(void* const* d_in, const int* in_sizes, int n_in,
                              void* d_out, int out_size, void* d_ws, size_t ws_size,
                              hipStream_t stream) {
    const float* feature = (const float*)d_in[0];
    const float* Wc0 = (const float*)d_in[1];
    const float* bc0 = (const float*)d_in[2];
    const float* We0a = (const float*)d_in[3];
    const float* be0a = (const float*)d_in[4];
    const float* We0b = (const float*)d_in[5];
    const float* be0b = (const float*)d_in[6];
    const float* Wc1 = (const float*)d_in[7];
    const float* bc1 = (const float*)d_in[8];
    const float* We1a = (const float*)d_in[9];
    const float* be1a = (const float*)d_in[10];
    const float* We1b = (const float*)d_in[11];
    const float* be1b = (const float*)d_in[12];
    const float* Wd0 = (const float*)d_in[13];
    const float* bd0 = (const float*)d_in[14];
    const float* Wd1 = (const float*)d_in[15];
    const float* bd1 = (const float*)d_in[16];
    const float* Wd2 = (const float*)d_in[17];
    const float* bd2 = (const float*)d_in[18];
    float* out = (float*)d_out;

    float* f = (float*)d_ws;
    // layout (floats), total ~30.7 MB with phase-based aliasing (JS=16 variant)
    float* x0   = f;                       // [0, 524288)
    float* x1   = f + 524288;              // [524288, 1048576)
    int*   idx0 = (int*)(f + 1048576);     // 196608
    int*   idx1 = (int*)(f + 1245184);     // 65536
    float* wT   = f + 1310720;             // 32768 (WbT0 | WbT1)
    float* Zab  = f + 1343488;             // 4194304: A | Bm
    float* Abuf = Zab;                     // 2097152
    float* Bbuf = Zab + 2097152;           // 2097152
    float* Y    = f + 5537792;             // 2097152: y0, later y1
    float* sq0  = f + 7634944;             // 16384
    float* sq1  = f + 7651328;             // 16384 (end 7667712)
    // kNN0 (JS=16, K=12): splits live in x1+idx slots (dead then); c0 spans Zab+Y
    unsigned short* xh0 = (unsigned short*)(f + 524288);    // 262144 floats (x1 lo)
    unsigned short* xm0 = (unsigned short*)(f + 786432);    // 262144 floats (x1 hi)
    unsigned short* xl0 = (unsigned short*)(f + 1048576);   // 262144 floats (idx0+idx1 slots)
    float* c0d  = f + 1343488;             // 3145728 (Zab + part of range)
    int*   c0i  = (int*)(f + 4489216);     // 3145728, ends 7634944 (rest of Zab + Y)
    // kNN1 (JS=16, K=4): splits + cands all inside Zab (Abuf/Bbuf from block0 dead)
    unsigned short* xh1 = (unsigned short*)Zab;             // 262144 floats
    unsigned short* xm1 = (unsigned short*)(Zab + 262144);
    unsigned short* xl1 = (unsigned short*)(Zab + 524288);
    float* c1d  = Zab + 786432;            // 1048576
    int*   c1i  = (int*)(Zab + 1835008);   // 1048576, ends Zab+2883584 < 4194304
    float* WbT0 = wT;
    float* WbT1 = wT + 16384;

    k_transpose_w<<<128, 256, 0, stream>>>(We0b, We1b, wT);
    k_conv_in<<<64, 256, 0, stream>>>(feature, Wc0, bc0, x0, sq0, xh0, xm0, xl0);
    k_knn_mfma<12, 16, 10><<<2048, 128, 0, stream>>>(xh0, xm0, xl0, sq0, c0d, c0i);
    k_knn_merge2<12, 16><<<128, 128, 0, stream>>>(c0d, c0i, idx0);
    k_premix<<<256, 256, 0, stream>>>(x0, We0a, be0a, Abuf, Bbuf);
    k_edgeconv4<12><<<256, 256, 0, stream>>>(idx0, Abuf, Bbuf, WbT0, be0b, Y);
    k_conv_mid<<<64, 256, 0, stream>>>(Y, Wc1, bc1, x1, sq1, xh1, xm1, xl1);
    k_knn_mfma<4, 16, 8><<<2048, 128, 0, stream>>>(xh1, xm1, xl1, sq1, c1d, c1i);
    k_knn_merge2<4, 16><<<128, 128, 0, stream>>>(c1d, c1i, idx1);
    k_premix<<<256, 256, 0, stream>>>(x1, We1a, be1a, Abuf, Bbuf);
    k_edgeconv4<4><<<256, 256, 0, stream>>>(idx1, Abuf, Bbuf, WbT1, be1b, Y);
    k_decoder<<<64, 256, 0, stream>>>(Y, Wd0, bd0, Wd1, bd1, Wd2, bd2, out);
}

// Round 26
// 623.621 us; speedup vs baseline: 1.0167x; 1.0167x over previous
//
#include <hip/hip_runtime.h>

#define NPTS 8192
#define NB 2

typedef __attribute__((ext_vector_type(8))) short short8v;   // 8 bf16 (4 VGPRs)
typedef __attribute__((ext_vector_type(4))) float f32x4;

__device__ __forceinline__ float lrelu(float x) { return x > 0.f ? x : 0.2f * x; }
__device__ __forceinline__ float4 lrelu4(float4 a) {
    return make_float4(lrelu(a.x), lrelu(a.y), lrelu(a.z), lrelu(a.w));
}
__device__ __forceinline__ float4 fmax4(float4 a, float4 b) {
    return make_float4(fmaxf(a.x, b.x), fmaxf(a.y, b.y), fmaxf(a.z, b.z), fmaxf(a.w, b.w));
}
__device__ __forceinline__ float4 add4(float4 a, float4 b) {
    return make_float4(a.x + b.x, a.y + b.y, a.z + b.z, a.w + b.w);
}
__device__ __forceinline__ unsigned short f2bf(float f) {     // RNE bf16
    unsigned int u = __float_as_uint(f);
    return (unsigned short)((u + 0x7FFFu + ((u >> 16) & 1u)) >> 16);
}
__device__ __forceinline__ float bf2f(unsigned short h) {
    return __uint_as_float(((unsigned int)h) << 16);
}
// multiply 8 packed bf16 by -2: exponent+1 (add 0x0080 per half) then sign flip.
// Exact pow-2 scaling for normal values; zero levels become +-2^-126 (error ~1e-38).
__device__ __forceinline__ short8v scale_m2(short8v v) {
    uint4 u = *(uint4*)&v;
    u.x = (u.x + 0x00800080u) ^ 0x80008000u;
    u.y = (u.y + 0x00800080u) ^ 0x80008000u;
    u.z = (u.z + 0x00800080u) ^ 0x80008000u;
    u.w = (u.w + 0x00800080u) ^ 0x80008000u;
    return *(short8v*)&u;
}

// ---------------- prep: transpose layer-2 weights into ws (WbT[c][o]) ----------------
__global__ void k_transpose_w(const float* __restrict__ Wb0, const float* __restrict__ Wb1,
                              float* __restrict__ out) {
    int t = blockIdx.x * 256 + threadIdx.x;
    if (t < 16384)      out[t] = Wb0[(t & 127) * 128 + (t >> 7)];
    else if (t < 32768) { int i = t - 16384; out[t] = Wb1[(i & 127) * 128 + (i >> 7)]; }
}

// 3-way bf16 split of a float4, packed into 2 uints per level
__device__ __forceinline__ void split3(float4 v, unsigned int* hp, unsigned int* mp,
                                       unsigned int* lp) {
    float c[4] = {v.x, v.y, v.z, v.w};
    unsigned short h[4], m[4], l[4];
    #pragma unroll
    for (int i = 0; i < 4; ++i) {
        h[i] = f2bf(c[i]);
        float r1 = c[i] - bf2f(h[i]);
        m[i] = f2bf(r1);
        float r2 = r1 - bf2f(m[i]);
        l[i] = f2bf(r2);
    }
    hp[0] = (unsigned int)h[0] | ((unsigned int)h[1] << 16);
    hp[1] = (unsigned int)h[2] | ((unsigned int)h[3] << 16);
    mp[0] = (unsigned int)m[0] | ((unsigned int)m[1] << 16);
    mp[1] = (unsigned int)m[2] | ((unsigned int)m[3] << 16);
    lp[0] = (unsigned int)l[0] | ((unsigned int)l[1] << 16);
    lp[1] = (unsigned int)l[2] | ((unsigned int)l[3] << 16);
}

// ---------------- conv_in: feature -> x0 fp32 + sq0 + bf16 h/m/l split ----------------
__global__ void k_conv_in(const float* __restrict__ f, const float* __restrict__ W,
                          const float* __restrict__ bias, float* __restrict__ out,
                          float* __restrict__ sq, unsigned short* __restrict__ xh,
                          unsigned short* __restrict__ xm, unsigned short* __restrict__ xl) {
    int gid = blockIdx.x * blockDim.x + threadIdx.x;   // over B*N
    int b = gid >> 13, n = gid & (NPTS - 1);
    const float* fb = f + ((size_t)b << 20) + n;       // b*128*8192
    float acc[32];
    #pragma unroll
    for (int o = 0; o < 32; ++o) acc[o] = bias[o];
    #pragma unroll 4
    for (int c = 0; c < 128; ++c) {
        float xc = fb[(size_t)c * NPTS];               // coalesced across lanes
        #pragma unroll
        for (int o = 0; o < 32; ++o) acc[o] += xc * W[o * 128 + c];  // uniform -> s_load
    }
    float s = 0.f;
    float4* op = (float4*)(out + (size_t)gid * 32);
    unsigned int* hrow = (unsigned int*)(xh + (size_t)gid * 32);
    unsigned int* mrow = (unsigned int*)(xm + (size_t)gid * 32);
    unsigned int* lrow = (unsigned int*)(xl + (size_t)gid * 32);
    #pragma unroll
    for (int o4 = 0; o4 < 8; ++o4) {
        float4 v = make_float4(lrelu(acc[o4 * 4]), lrelu(acc[o4 * 4 + 1]),
                               lrelu(acc[o4 * 4 + 2]), lrelu(acc[o4 * 4 + 3]));
        s += v.x * v.x + v.y * v.y + v.z * v.z + v.w * v.w;
        op[o4] = v;
        unsigned int hp[2], mp[2], lp[2];
        split3(v, hp, mp, lp);
        *(uint2*)(hrow + o4 * 2) = make_uint2(hp[0], hp[1]);
        *(uint2*)(mrow + o4 * 2) = make_uint2(mp[0], mp[1]);
        *(uint2*)(lrow + o4 * 2) = make_uint2(lp[0], lp[1]);
    }
    sq[gid] = s;
}

// ---------------- premix: A = x @ Wa1^T ; Bm = x @ (Wa2-Wa1)^T + ba ----------------
// (256,2): 128-VGPR budget so xv[8]+acc[32] stay in registers (R19 fix).
__global__ __launch_bounds__(256, 2) void k_premix(const float* __restrict__ x,
                                                   const float* __restrict__ Wa,
                                                   const float* __restrict__ ba,
                                                   float* __restrict__ A,
                                                   float* __restrict__ Bm) {
    int tid = threadIdx.x;
    int q = tid >> 6;                       // quarter (wave-uniform)
    int p = blockIdx.x * 64 + (tid & 63);   // point over NB*NPTS
    float4 xv[8];
    {
        const float4* xr = (const float4*)(x + (size_t)p * 32);
        #pragma unroll
        for (int u = 0; u < 8; ++u) xv[u] = xr[u];
    }
    const float* W0 = Wa + q * 32 * 64;     // rows q*32..q*32+31
    float acc[32];
    #pragma unroll
    for (int o = 0; o < 32; ++o) acc[o] = 0.f;
    #pragma unroll 2
    for (int c4 = 0; c4 < 8; ++c4) {
        float4 v = xv[c4];
        #pragma unroll
        for (int o = 0; o < 32; ++o) {
            const float* w = W0 + o * 64 + c4 * 4;   // uniform -> s_load
            acc[o] += v.x * w[0] + v.y * w[1] + v.z * w[2] + v.w * w[3];
        }
    }
    {
        float4* op = (float4*)(A + (size_t)p * 128 + q * 32);
        #pragma unroll
        for (int o4 = 0; o4 < 8; ++o4)
            op[o4] = make_float4(acc[o4 * 4], acc[o4 * 4 + 1], acc[o4 * 4 + 2], acc[o4 * 4 + 3]);
    }
    #pragma unroll
    for (int o = 0; o < 32; ++o) acc[o] = ba[q * 32 + o];
    #pragma unroll 2
    for (int c4 = 0; c4 < 8; ++c4) {
        float4 v = xv[c4];
        #pragma unroll
        for (int o = 0; o < 32; ++o) {
            const float* w1 = W0 + o * 64 + c4 * 4;
            const float* w2 = w1 + 32;
            acc[o] += v.x * (w2[0] - w1[0]) + v.y * (w2[1] - w1[1]) +
                      v.z * (w2[2] - w1[2]) + v.w * (w2[3] - w1[3]);
        }
    }
    {
        float4* op = (float4*)(Bm + (size_t)p * 128 + q * 32);
        #pragma unroll
        for (int o4 = 0; o4 < 8; ++o4)
            op[o4] = make_float4(acc[o4 * 4], acc[o4 * 4 + 1], acc[o4 * 4 + 2], acc[o4 * 4 + 3]);
    }
}

// ---------------- kNN via MFMA Gram, rank key fused into MFMA ----------------
// R25 diagnosis: VALU-issue-bound (70% busy, latency fixes null). Cuts:
// (1) A-frags scaled by -2 in-register + acc init = sq_j -> Dl holds the rank
//     key directly (selection loses SQl read + fma per j);
// (2) (d,j) packed into one ds_write_b64 per append;
// (3) flush loop bounded by wave-max cnt instead of C.
template <int K, int JS, int C>
__global__ __launch_bounds__(128, 2) void k_knn_mfma(const unsigned short* __restrict__ xh,
                                                     const unsigned short* __restrict__ xm,
                                                     const unsigned short* __restrict__ xl,
                                                     const float* __restrict__ sqg,
                                                     float* __restrict__ cand_d,
                                                     int* __restrict__ cand_i) {
    constexpr int IT = 128;                  // i-tile
    constexpr int JR = NPTS / JS;            // 512 for JS=16
    constexpr int NCH = JR / 16;             // chunks of 16 j
    constexpr int BPB = (NPTS / IT) * JS;    // blocks per batch
    constexpr int DS = 17;                   // Dl row stride (reads 2-way free)

    __shared__ float Dl[IT * DS];
    __shared__ unsigned long long bufe[C * IT];   // packed (d<<32)|j, conflict-free cols

    int tid = threadIdx.x;
    int bid = blockIdx.x;
    int b = bid / BPB;
    int r0b = bid - b * BPB;
    int itile = r0b / JS;
    int jseg = r0b - itile * JS;

    const unsigned short* xhb = xh + ((size_t)b * NPTS) * 32;
    const unsigned short* xmb = xm + ((size_t)b * NPTS) * 32;
    const unsigned short* xlb = xl + ((size_t)b * NPTS) * 32;
    const float* sqb = sqg + (size_t)b * NPTS;

    int lane = tid & 63;
    int w = tid >> 6;          // wave 0..1 -> i rows [w*64, w*64+64)
    int g = lane >> 4;         // k-group: k = g*8 + e
    int r15 = lane & 15;

    // A fragments hoisted, scaled by -2 (rank-key fusion), pinned
    short8v ah[4], am[4], al[4];
    #pragma unroll
    for (int t = 0; t < 4; ++t) {
        size_t ii = (size_t)(itile * IT + w * 64 + t * 16 + r15);
        ah[t] = scale_m2(*(const short8v*)(xhb + ii * 32 + g * 8));
        am[t] = scale_m2(*(const short8v*)(xmb + ii * 32 + g * 8));
        al[t] = scale_m2(*(const short8v*)(xlb + ii * 32 + g * 8));
    }
    #pragma unroll
    for (int t = 0; t < 4; ++t) {
        asm volatile("" : "+v"(ah[t]));
        asm volatile("" : "+v"(am[t]));
        asm volatile("" : "+v"(al[t]));
    }

    float bd[K]; int bi[K];                  // sorted ascending, registers
    #pragma unroll
    for (int r = 0; r < K; ++r) { bd[r] = 1e30f; bi[r] = 0; }
    float thr = 1e30f;
    int cnt = 0;

    auto flush = [&]() {
        int mc = cnt;                         // wave-max cnt (uniform loop bound)
        #pragma unroll
        for (int off = 1; off < 64; off <<= 1) {
            int o = __shfl_xor(mc, off);
            mc = mc > o ? mc : o;
        }
        #pragma unroll 1
        for (int u = 0; u < mc; ++u) {
            unsigned long long e = bufe[u * IT + tid];
            bool valid = u < cnt;
            float dd = valid ? __uint_as_float((unsigned int)(e >> 32)) : 1e30f;
            int ji = (int)(unsigned int)e;
            #pragma unroll
            for (int r = 0; r < K; ++r) {
                bool c = dd < bd[r];
                float tf = bd[r]; int ti = bi[r];
                bd[r] = c ? dd : bd[r]; bi[r] = c ? ji : bi[r];
                dd = c ? tf : dd;       ji = c ? ti : ji;
            }
        }
        cnt = 0; thr = bd[K - 1];
    };

#define LOADBS_(J, BH, BM, BL, SV)                                             \
    do {                                                                       \
        size_t ja_ = (size_t)(J) + r15;                                        \
        BH = *(const short8v*)(xhb + ja_ * 32 + g * 8);                        \
        BM = *(const short8v*)(xmb + ja_ * 32 + g * 8);                        \
        BL = *(const short8v*)(xlb + ja_ * 32 + g * 8);                        \
        SV = sqb[(size_t)(J) + r15];                                           \
    } while (0)

#define MFMA_(BH, BM, BL, SV)                                                  \
    do {                                                                       \
        _Pragma("unroll")                                                      \
        for (int t = 0; t < 4; ++t) {                                          \
            f32x4 acc = {SV, SV, SV, SV};                                      \
            acc = __builtin_amdgcn_mfma_f32_16x16x32_bf16(am[t], BM, acc, 0, 0, 0); \
            acc = __builtin_amdgcn_mfma_f32_16x16x32_bf16(ah[t], BL, acc, 0, 0, 0); \
            acc = __builtin_amdgcn_mfma_f32_16x16x32_bf16(al[t], BH, acc, 0, 0, 0); \
            acc = __builtin_amdgcn_mfma_f32_16x16x32_bf16(ah[t], BM, acc, 0, 0, 0); \
            acc = __builtin_amdgcn_mfma_f32_16x16x32_bf16(am[t], BH, acc, 0, 0, 0); \
            acc = __builtin_amdgcn_mfma_f32_16x16x32_bf16(ah[t], BH, acc, 0, 0, 0); \
            int il_ = w * 64 + t * 16 + g * 4;                                 \
            Dl[(il_ + 0) * DS + r15] = acc[0];                                 \
            Dl[(il_ + 1) * DS + r15] = acc[1];                                 \
            Dl[(il_ + 2) * DS + r15] = acc[2];                                 \
            Dl[(il_ + 3) * DS + r15] = acc[3];                                 \
        }                                                                      \
    } while (0)

#define PACK_(D, J) ((((unsigned long long)__float_as_uint(D)) << 32) | (unsigned int)(J))

#define SELECT_(J0)                                                            \
    do {                                                                       \
        _Pragma("unroll 1")                                                    \
        for (int jq = 0; jq < 16; jq += 4) {                                   \
            float d0 = Dl[tid * DS + jq + 0];                                  \
            float d1 = Dl[tid * DS + jq + 1];                                  \
            float d2 = Dl[tid * DS + jq + 2];                                  \
            float d3 = Dl[tid * DS + jq + 3];                                  \
            int j_ = (J0) + jq;                                                \
            if (d0 < thr) { bufe[cnt * IT + tid] = PACK_(d0, j_ + 0); cnt++; } \
            if (d1 < thr) { bufe[cnt * IT + tid] = PACK_(d1, j_ + 1); cnt++; } \
            if (d2 < thr) { bufe[cnt * IT + tid] = PACK_(d2, j_ + 2); cnt++; } \
            if (d3 < thr) { bufe[cnt * IT + tid] = PACK_(d3, j_ + 3); cnt++; } \
            if (__any(cnt >= C - 3)) flush();                                  \
        }                                                                      \
    } while (0)

    int jbase = jseg * JR;
    short8v bhA, bmA, blA, bhB, bmB, blB;
    float svA, svB;
    LOADBS_(jbase, bhA, bmA, blA, svA);      // prologue: B + sq for chunk 0
    #pragma unroll 1
    for (int ch = 0; ch < NCH; ch += 2) {
        int j0 = jbase + ch * 16;
        int j1 = j0 + 16;
        // ---- body A (chunk ch) ----
        LOADBS_(j1, bhB, bmB, blB, svB);     // prefetch chunk ch+1
        MFMA_(bhA, bmA, blA, svA);
        SELECT_(j0);
        // ---- body B (chunk ch+1) ----
        int j2 = (ch + 2 < NCH) ? j1 + 16 : jbase;   // clamp tail (harmless refetch)
        LOADBS_(j2, bhA, bmA, blA, svA);     // prefetch next pair
        MFMA_(bhB, bmB, blB, svB);
        SELECT_(j1);
    }
    flush();
#undef LOADBS_
#undef MFMA_
#undef PACK_
#undef SELECT_
    size_t base = ((size_t)jseg * (NB * NPTS) + (size_t)(b * NPTS) + itile * IT + tid) * K;
    #pragma unroll
    for (int r = 0; r < K; ++r) { cand_d[base + r] = bd[r]; cand_i[base + r] = bi[r]; }
}

// ---------------- merge v2: register insertion-chain with per-segment early exit ----------------
template <int K, int JS>
__global__ __launch_bounds__(128, 4) void k_knn_merge2(const float* __restrict__ cand_d,
                                                       const int* __restrict__ cand_i,
                                                       int* __restrict__ idx_out) {
    int p = blockIdx.x * 128 + threadIdx.x;   // over NB*NPTS
    float bd[K]; int bi[K];
    #pragma unroll
    for (int r = 0; r < K; ++r) { bd[r] = 1e30f; bi[r] = 0; }
    float thr = 1e30f;
    #pragma unroll 1
    for (int s = 0; s < JS; ++s) {
        size_t base = ((size_t)s * (NB * NPTS) + p) * K;
        #pragma unroll 1
        for (int r = 0; r < K; ++r) {
            float d = cand_d[base + r];
            if (!(d < thr)) break;            // sorted: rest of segment can't insert
            int j = cand_i[base + r];
            float dd = d; int ji = j;
            #pragma unroll
            for (int q = 0; q < K; ++q) {
                bool c = dd < bd[q];
                float tf = bd[q]; int ti = bi[q];
                bd[q] = c ? dd : bd[q]; bi[q] = c ? ji : bi[q];
                dd = c ? tf : dd;       ji = c ? ti : ji;
            }
            thr = bd[K - 1];
        }
    }
    int* op = idx_out + (size_t)p * K;
    #pragma unroll
    for (int r = 0; r < K; ++r) op[r] = bi[r];
}

// ---------------- EdgeConv v4: register-lean 6x8 / 4x8 output tiles ----------------
template <int K>
__global__ __launch_bounds__(256, 1)
void k_edgeconv4(const int* __restrict__ idx,
                 const float* __restrict__ A, const float* __restrict__ Bm,
                 const float* __restrict__ WbTg, const float* __restrict__ bb,
                 float* __restrict__ y) {
    constexpr int TE = (K == 12) ? 6 : 4;     // edges per thread
    constexpr int EPI = 16 * TE;              // edges per iter: 96 / 64
    constexpr int PI = EPI / K;               // points per iter: 8 / 16
    constexpr int ITERS = 64 / PI;            // 8 / 4
    constexpr int NT = 256;
    constexpr int HS = 132;                   // H1 row stride

    __shared__ __align__(16) float WbT[128 * 128];
    __shared__ __align__(16) float bb_s[128];
    __shared__ __align__(16) float H1[EPI * HS];
    __shared__ __align__(16) float Pm[(K == 12) ? 16 * 128 : 4];

    int tid = threadIdx.x;
    {
        const float4* sb = (const float4*)WbTg;
        float4* db = (float4*)WbT;
        #pragma unroll
        for (int i = 0; i < 16; ++i) db[tid + i * NT] = sb[tid + i * NT];
        if (tid < 128) bb_s[tid] = bb[tid];
    }

    int b = blockIdx.x >> 7;
    int pbase = (blockIdx.x & 127) * 64;
    const int* idxb = idx + ((size_t)b * NPTS) * K;
    const float4* A4 = (const float4*)(A + ((size_t)b * NPTS) * 128);
    const float4* B4 = (const float4*)(Bm + ((size_t)b * NPTS) * 128);
    float* yb = y + ((size_t)b * NPTS) * 128;

    int og = tid & 15;        // 16 out-groups x 8 outputs
    int eg = tid >> 4;        // 16 edge-groups x TE edges
    int ebase = eg * TE;

    for (int it = 0; it < ITERS; ++it) {
        int pt0 = pbase + it * PI;
        #pragma unroll
        for (int r = 0; r < (EPI * 32) / NT; ++r) {
            int u = tid + r * NT;
            int e = u >> 5, c4 = u & 31;
            int p = pt0 + e / K;
            int j = idxb[(size_t)p * K + (e % K)];
            float4 av = A4[(size_t)j * 32 + c4];
            float4 bv = B4[(size_t)p * 32 + c4];
            *(float4*)&H1[e * HS + 4 * c4] = lrelu4(add4(av, bv));
        }
        __syncthreads();
        float4 acc[TE][2];
        {
            float4 blo = *(const float4*)&bb_s[og * 8];
            float4 bhi = *(const float4*)&bb_s[og * 8 + 4];
            #pragma unroll
            for (int e = 0; e < TE; ++e) { acc[e][0] = blo; acc[e][1] = bhi; }
        }
        #pragma unroll 2
        for (int c4 = 0; c4 < 32; ++c4) {
            float4 hv[TE];
            #pragma unroll
            for (int e = 0; e < TE; ++e)
                hv[e] = *(const float4*)&H1[(ebase + e) * HS + 4 * c4];
            #pragma unroll
            for (int j = 0; j < 4; ++j) {
                const float* wr = &WbT[(4 * c4 + j) * 128 + og * 8];
                float4 wlo = *(const float4*)wr;
                float4 whi = *(const float4*)(wr + 4);
                #pragma unroll
                for (int e = 0; e < TE; ++e) {
                    float hc = (j == 0) ? hv[e].x : (j == 1) ? hv[e].y : (j == 2) ? hv[e].z : hv[e].w;
                    acc[e][0].x += hc * wlo.x; acc[e][0].y += hc * wlo.y;
                    acc[e][0].z += hc * wlo.z; acc[e][0].w += hc * wlo.w;
                    acc[e][1].x += hc * whi.x; acc[e][1].y += hc * whi.y;
                    acc[e][1].z += hc * whi.z; acc[e][1].w += hc * whi.w;
                }
            }
        }
        float4 mlo = lrelu4(acc[0][0]), mhi = lrelu4(acc[0][1]);
        #pragma unroll
        for (int e = 1; e < TE; ++e) {
            mlo = fmax4(mlo, lrelu4(acc[e][0]));
            mhi = fmax4(mhi, lrelu4(acc[e][1]));
        }
        if constexpr (K == 4) {
            float4* yp = (float4*)&yb[((size_t)(pt0 + eg)) * 128 + og * 8];
            yp[0] = mlo; yp[1] = mhi;
            __syncthreads();
        } else {
            *(float4*)&Pm[eg * 128 + og * 8] = mlo;
            *(float4*)&Pm[eg * 128 + og * 8 + 4] = mhi;
            __syncthreads();
            #pragma unroll
            for (int r = 0; r < 4; ++r) {
                int u = tid + r * NT;
                int p = u >> 7, o = u & 127;
                yb[((size_t)(pt0 + p)) * 128 + o] =
                    fmaxf(Pm[(2 * p) * 128 + o], Pm[(2 * p + 1) * 128 + o]);
            }
        }
    }
}

// ---------------- conv_mid: y -> x1 fp32 + sq1 + bf16 h/m/l split ----------------
__global__ void k_conv_mid(const float* __restrict__ xin, const float* __restrict__ W,
                           const float* __restrict__ bias, float* __restrict__ out,
                           float* __restrict__ sq, unsigned short* __restrict__ xh,
                           unsigned short* __restrict__ xm, unsigned short* __restrict__ xl) {
    int gid = blockIdx.x * blockDim.x + threadIdx.x;
    const float4* row = (const float4*)(xin + (size_t)gid * 128);
    float acc[32];
    #pragma unroll
    for (int o = 0; o < 32; ++o) acc[o] = bias[o];
    #pragma unroll 2
    for (int c4 = 0; c4 < 32; ++c4) {
        float4 v = row[c4];
        #pragma unroll
        for (int o = 0; o < 32; ++o) {
            const float* w = W + o * 128 + c4 * 4;   // uniform -> s_load
            acc[o] += v.x * w[0] + v.y * w[1] + v.z * w[2] + v.w * w[3];
        }
    }
    float s = 0.f;
    float4* op = (float4*)(out + (size_t)gid * 32);
    unsigned int* hrow = (unsigned int*)(xh + (size_t)gid * 32);
    unsigned int* mrow = (unsigned int*)(xm + (size_t)gid * 32);
    unsigned int* lrow = (unsigned int*)(xl + (size_t)gid * 32);
    #pragma unroll
    for (int o4 = 0; o4 < 8; ++o4) {
        float4 v = make_float4(lrelu(acc[o4 * 4]), lrelu(acc[o4 * 4 + 1]),
                               lrelu(acc[o4 * 4 + 2]), lrelu(acc[o4 * 4 + 3]));
        s += v.x * v.x + v.y * v.y + v.z * v.z + v.w * v.w;
        op[o4] = v;
        unsigned int hp[2], mp[2], lp[2];
        split3(v, hp, mp, lp);
        *(uint2*)(hrow + o4 * 2) = make_uint2(hp[0], hp[1]);
        *(uint2*)(mrow + o4 * 2) = make_uint2(mp[0], mp[1]);
        *(uint2*)(lrow + o4 * 2) = make_uint2(lp[0], lp[1]);
    }
    sq[gid] = s;
}

// ---------------- decoder: y1 [B*N,128] -> out [B*N,12] ----------------
__global__ void k_decoder(const float* __restrict__ xin,
                          const float* __restrict__ W0, const float* __restrict__ b0,
                          const float* __restrict__ W1, const float* __restrict__ b1,
                          const float* __restrict__ W2, const float* __restrict__ b2,
                          float* __restrict__ out) {
    int gid = blockIdx.x * blockDim.x + threadIdx.x;
    const float4* row = (const float4*)(xin + (size_t)gid * 128);
    float h0[6];
    #pragma unroll
    for (int o = 0; o < 6; ++o) h0[o] = b0[o];
    #pragma unroll 4
    for (int c4 = 0; c4 < 32; ++c4) {
        float4 v = row[c4];
        #pragma unroll
        for (int o = 0; o < 6; ++o) {
            const float* w = W0 + o * 128 + c4 * 4;
            h0[o] += v.x * w[0] + v.y * w[1] + v.z * w[2] + v.w * w[3];
        }
    }
    #pragma unroll
    for (int o = 0; o < 6; ++o) h0[o] = lrelu(h0[o]);
    float h1[12];
    #pragma unroll
    for (int o = 0; o < 12; ++o) {
        float a = b1[o];
        #pragma unroll
        for (int j = 0; j < 6; ++j) a += W1[o * 6 + j] * h0[j];
        h1[o] = lrelu(a);
    }
    float* op = out + (size_t)gid * 12;
    #pragma unroll
    for (int o = 0; o < 12; ++o) {
        float a = b2[o];
        #pragma unroll
        for (int j = 0; j < 12; ++j) a += W2[o * 12 + j] * h1[j];
        op[o] = a;
    }
}

extern "C" void kernel_launch(void* const* d_in, const int* in_sizes, int n_in,
                              void* d_out, int out_size, void* d_ws, size_t ws_size,
                              hipStream_t stream) {
    const float* feature = (const float*)d_in[0];
    const float* Wc0 = (const float*)d_in[1];
    const float* bc0 = (const float*)d_in[2];
    const float* We0a = (const float*)d_in[3];
    const float* be0a = (const float*)d_in[4];
    const float* We0b = (const float*)d_in[5];
    const float* be0b = (const float*)d_in[6];
    const float* Wc1 = (const float*)d_in[7];
    const float* bc1 = (const float*)d_in[8];
    const float* We1a = (const float*)d_in[9];
    const float* be1a = (const float*)d_in[10];
    const float* We1b = (const float*)d_in[11];
    const float* be1b = (const float*)d_in[12];
    const float* Wd0 = (const float*)d_in[13];
    const float* bd0 = (const float*)d_in[14];
    const float* Wd1 = (const float*)d_in[15];
    const float* bd1 = (const float*)d_in[16];
    const float* Wd2 = (const float*)d_in[17];
    const float* bd2 = (const float*)d_in[18];
    float* out = (float*)d_out;

    float* f = (float*)d_ws;
    // layout (floats), total ~30.7 MB with phase-based aliasing (JS=16 variant)
    float* x0   = f;                       // [0, 524288)
    float* x1   = f + 524288;              // [524288, 1048576)
    int*   idx0 = (int*)(f + 1048576);     // 196608
    int*   idx1 = (int*)(f + 1245184);     // 65536
    float* wT   = f + 1310720;             // 32768 (WbT0 | WbT1)
    float* Zab  = f + 1343488;             // 4194304: A | Bm
    float* Abuf = Zab;                     // 2097152
    float* Bbuf = Zab + 2097152;           // 2097152
    float* Y    = f + 5537792;             // 2097152: y0, later y1
    float* sq0  = f + 7634944;             // 16384
    float* sq1  = f + 7651328;             // 16384 (end 7667712)
    // kNN0 (JS=16, K=12): splits live in x1+idx slots (dead then); c0 spans Zab+Y
    unsigned short* xh0 = (unsigned short*)(f + 524288);    // 262144 floats (x1 lo)
    unsigned short* xm0 = (unsigned short*)(f + 786432);    // 262144 floats (x1 hi)
    unsigned short* xl0 = (unsigned short*)(f + 1048576);   // 262144 floats (idx0+idx1 slots)
    float* c0d  = f + 1343488;             // 3145728 (Zab + part of range)
    int*   c0i  = (int*)(f + 4489216);     // 3145728, ends 7634944 (rest of Zab + Y)
    // kNN1 (JS=16, K=4): splits + cands all inside Zab (Abuf/Bbuf from block0 dead)
    unsigned short* xh1 = (unsigned short*)Zab;             // 262144 floats
    unsigned short* xm1 = (unsigned short*)(Zab + 262144);
    unsigned short* xl1 = (unsigned short*)(Zab + 524288);
    float* c1d  = Zab + 786432;            // 1048576
    int*   c1i  = (int*)(Zab + 1835008);   // 1048576, ends Zab+2883584 < 4194304
    float* WbT0 = wT;
    float* WbT1 = wT + 16384;

    k_transpose_w<<<128, 256, 0, stream>>>(We0b, We1b, wT);
    k_conv_in<<<64, 256, 0, stream>>>(feature, Wc0, bc0, x0, sq0, xh0, xm0, xl0);
    k_knn_mfma<12, 16, 10><<<2048, 128, 0, stream>>>(xh0, xm0, xl0, sq0, c0d, c0i);
    k_knn_merge2<12, 16><<<128, 128, 0, stream>>>(c0d, c0i, idx0);
    k_premix<<<256, 256, 0, stream>>>(x0, We0a, be0a, Abuf, Bbuf);
    k_edgeconv4<12><<<256, 256, 0, stream>>>(idx0, Abuf, Bbuf, WbT0, be0b, Y);
    k_conv_mid<<<64, 256, 0, stream>>>(Y, Wc1, bc1, x1, sq1, xh1, xm1, xl1);
    k_knn_mfma<4, 16, 8><<<2048, 128, 0, stream>>>(xh1, xm1, xl1, sq1, c1d, c1i);
    k_knn_merge2<4, 16><<<128, 128, 0, stream>>>(c1d, c1i, idx1);
    k_premix<<<256, 256, 0, stream>>>(x1, We1a, be1a, Abuf, Bbuf);
    k_edgeconv4<4><<<256, 256, 0, stream>>>(idx1, Abuf, Bbuf, WbT1, be1b, Y);
    k_decoder<<<64, 256, 0, stream>>>(Y, Wd0, bd0, Wd1, bd1, Wd2, bd2, out);
}

// Round 27
// 584.054 us; speedup vs baseline: 1.0856x; 1.0677x over previous
//
#include <hip/hip_runtime.h>

#define NPTS 8192
#define NB 2

typedef __attribute__((ext_vector_type(8))) short short8v;   // 8 bf16 (4 VGPRs)
typedef __attribute__((ext_vector_type(4))) float f32x4;

__device__ __forceinline__ float lrelu(float x) { return x > 0.f ? x : 0.2f * x; }
__device__ __forceinline__ float4 lrelu4(float4 a) {
    return make_float4(lrelu(a.x), lrelu(a.y), lrelu(a.z), lrelu(a.w));
}
__device__ __forceinline__ unsigned short f2bf(float f) {     // RNE bf16
    unsigned int u = __float_as_uint(f);
    return (unsigned short)((u + 0x7FFFu + ((u >> 16) & 1u)) >> 16);
}
__device__ __forceinline__ float bf2f(unsigned short h) {
    return __uint_as_float(((unsigned int)h) << 16);
}
// multiply 8 packed bf16 by -2: exponent+1 then sign flip (exact pow-2 scale)
__device__ __forceinline__ short8v scale_m2(short8v v) {
    uint4 u = *(uint4*)&v;
    u.x = (u.x + 0x00800080u) ^ 0x80008000u;
    u.y = (u.y + 0x00800080u) ^ 0x80008000u;
    u.z = (u.z + 0x00800080u) ^ 0x80008000u;
    u.w = (u.w + 0x00800080u) ^ 0x80008000u;
    return *(short8v*)&u;
}

// 3-way bf16 split of a float4, packed into 2 uints per level
__device__ __forceinline__ void split3(float4 v, unsigned int* hp, unsigned int* mp,
                                       unsigned int* lp) {
    float c[4] = {v.x, v.y, v.z, v.w};
    unsigned short h[4], m[4], l[4];
    #pragma unroll
    for (int i = 0; i < 4; ++i) {
        h[i] = f2bf(c[i]);
        float r1 = c[i] - bf2f(h[i]);
        m[i] = f2bf(r1);
        float r2 = r1 - bf2f(m[i]);
        l[i] = f2bf(r2);
    }
    hp[0] = (unsigned int)h[0] | ((unsigned int)h[1] << 16);
    hp[1] = (unsigned int)h[2] | ((unsigned int)h[3] << 16);
    mp[0] = (unsigned int)m[0] | ((unsigned int)m[1] << 16);
    mp[1] = (unsigned int)m[2] | ((unsigned int)m[3] << 16);
    lp[0] = (unsigned int)l[0] | ((unsigned int)l[1] << 16);
    lp[1] = (unsigned int)l[2] | ((unsigned int)l[3] << 16);
}

// ---------------- prepack Wb (both layers) into MFMA B-fragment order, bf16 hi/lo ----------------
// Element (L, level v, kc, nt, lane, e): B[k][n] = WbL[n][k], k = kc*32+(lane>>4)*8+e,
// n = nt*16+(lane&15). Layout: out[(L*2+v)*16384 + (kc*8+nt)*512 + lane*8 + e].
__global__ void k_prepack_wb(const float* __restrict__ Wb0, const float* __restrict__ Wb1,
                             unsigned short* __restrict__ out) {
    int t = blockIdx.x * 256 + threadIdx.x;    // 32768 threads
    int L = t >> 14;
    int idx = t & 16383;
    int frag = idx >> 9;                        // kc*8 + nt
    int lane = (idx >> 3) & 63;
    int e = idx & 7;
    int kc = frag >> 3, nt = frag & 7;
    int k = kc * 32 + (lane >> 4) * 8 + e;
    int n = nt * 16 + (lane & 15);
    const float* Wb = L ? Wb1 : Wb0;
    float val = Wb[n * 128 + k];
    unsigned short hi = f2bf(val);
    unsigned short lo = f2bf(val - bf2f(hi));
    out[(L * 2 + 0) * 16384 + idx] = hi;
    out[(L * 2 + 1) * 16384 + idx] = lo;
}

// ---------------- conv_in: feature -> x0 fp32 + sq0 + bf16 h/m/l split ----------------
__global__ void k_conv_in(const float* __restrict__ f, const float* __restrict__ W,
                          const float* __restrict__ bias, float* __restrict__ out,
                          float* __restrict__ sq, unsigned short* __restrict__ xh,
                          unsigned short* __restrict__ xm, unsigned short* __restrict__ xl) {
    int gid = blockIdx.x * blockDim.x + threadIdx.x;   // over B*N
    int b = gid >> 13, n = gid & (NPTS - 1);
    const float* fb = f + ((size_t)b << 20) + n;       // b*128*8192
    float acc[32];
    #pragma unroll
    for (int o = 0; o < 32; ++o) acc[o] = bias[o];
    #pragma unroll 4
    for (int c = 0; c < 128; ++c) {
        float xc = fb[(size_t)c * NPTS];               // coalesced across lanes
        #pragma unroll
        for (int o = 0; o < 32; ++o) acc[o] += xc * W[o * 128 + c];  // uniform -> s_load
    }
    float s = 0.f;
    float4* op = (float4*)(out + (size_t)gid * 32);
    unsigned int* hrow = (unsigned int*)(xh + (size_t)gid * 32);
    unsigned int* mrow = (unsigned int*)(xm + (size_t)gid * 32);
    unsigned int* lrow = (unsigned int*)(xl + (size_t)gid * 32);
    #pragma unroll
    for (int o4 = 0; o4 < 8; ++o4) {
        float4 v = make_float4(lrelu(acc[o4 * 4]), lrelu(acc[o4 * 4 + 1]),
                               lrelu(acc[o4 * 4 + 2]), lrelu(acc[o4 * 4 + 3]));
        s += v.x * v.x + v.y * v.y + v.z * v.z + v.w * v.w;
        op[o4] = v;
        unsigned int hp[2], mp[2], lp[2];
        split3(v, hp, mp, lp);
        *(uint2*)(hrow + o4 * 2) = make_uint2(hp[0], hp[1]);
        *(uint2*)(mrow + o4 * 2) = make_uint2(mp[0], mp[1]);
        *(uint2*)(lrow + o4 * 2) = make_uint2(lp[0], lp[1]);
    }
    sq[gid] = s;
}

// ---------------- premix: A = x @ Wa1^T ; Bm = x @ (Wa2-Wa1)^T + ba ----------------
__global__ __launch_bounds__(256, 2) void k_premix(const float* __restrict__ x,
                                                   const float* __restrict__ Wa,
                                                   const float* __restrict__ ba,
                                                   float* __restrict__ A,
                                                   float* __restrict__ Bm) {
    int tid = threadIdx.x;
    int q = tid >> 6;                       // quarter (wave-uniform)
    int p = blockIdx.x * 64 + (tid & 63);   // point over NB*NPTS
    float4 xv[8];
    {
        const float4* xr = (const float4*)(x + (size_t)p * 32);
        #pragma unroll
        for (int u = 0; u < 8; ++u) xv[u] = xr[u];
    }
    const float* W0 = Wa + q * 32 * 64;     // rows q*32..q*32+31
    float acc[32];
    #pragma unroll
    for (int o = 0; o < 32; ++o) acc[o] = 0.f;
    #pragma unroll 2
    for (int c4 = 0; c4 < 8; ++c4) {
        float4 v = xv[c4];
        #pragma unroll
        for (int o = 0; o < 32; ++o) {
            const float* w = W0 + o * 64 + c4 * 4;   // uniform -> s_load
            acc[o] += v.x * w[0] + v.y * w[1] + v.z * w[2] + v.w * w[3];
        }
    }
    {
        float4* op = (float4*)(A + (size_t)p * 128 + q * 32);
        #pragma unroll
        for (int o4 = 0; o4 < 8; ++o4)
            op[o4] = make_float4(acc[o4 * 4], acc[o4 * 4 + 1], acc[o4 * 4 + 2], acc[o4 * 4 + 3]);
    }
    #pragma unroll
    for (int o = 0; o < 32; ++o) acc[o] = ba[q * 32 + o];
    #pragma unroll 2
    for (int c4 = 0; c4 < 8; ++c4) {
        float4 v = xv[c4];
        #pragma unroll
        for (int o = 0; o < 32; ++o) {
            const float* w1 = W0 + o * 64 + c4 * 4;
            const float* w2 = w1 + 32;
            acc[o] += v.x * (w2[0] - w1[0]) + v.y * (w2[1] - w1[1]) +
                      v.z * (w2[2] - w1[2]) + v.w * (w2[3] - w1[3]);
        }
    }
    {
        float4* op = (float4*)(Bm + (size_t)p * 128 + q * 32);
        #pragma unroll
        for (int o4 = 0; o4 < 8; ++o4)
            op[o4] = make_float4(acc[o4 * 4], acc[o4 * 4 + 1], acc[o4 * 4 + 2], acc[o4 * 4 + 3]);
    }
}

// ---------------- kNN via MFMA Gram, rank key fused into MFMA (R26 version) ----------------
template <int K, int JS, int C>
__global__ __launch_bounds__(128, 2) void k_knn_mfma(const unsigned short* __restrict__ xh,
                                                     const unsigned short* __restrict__ xm,
                                                     const unsigned short* __restrict__ xl,
                                                     const float* __restrict__ sqg,
                                                     float* __restrict__ cand_d,
                                                     int* __restrict__ cand_i) {
    constexpr int IT = 128;                  // i-tile
    constexpr int JR = NPTS / JS;            // 512 for JS=16
    constexpr int NCH = JR / 16;             // chunks of 16 j
    constexpr int BPB = (NPTS / IT) * JS;    // blocks per batch
    constexpr int DS = 17;                   // Dl row stride (reads 2-way free)

    __shared__ float Dl[IT * DS];
    __shared__ unsigned long long bufe[C * IT];   // packed (d<<32)|j, conflict-free cols

    int tid = threadIdx.x;
    int bid = blockIdx.x;
    int b = bid / BPB;
    int r0b = bid - b * BPB;
    int itile = r0b / JS;
    int jseg = r0b - itile * JS;

    const unsigned short* xhb = xh + ((size_t)b * NPTS) * 32;
    const unsigned short* xmb = xm + ((size_t)b * NPTS) * 32;
    const unsigned short* xlb = xl + ((size_t)b * NPTS) * 32;
    const float* sqb = sqg + (size_t)b * NPTS;

    int lane = tid & 63;
    int w = tid >> 6;          // wave 0..1 -> i rows [w*64, w*64+64)
    int g = lane >> 4;         // k-group: k = g*8 + e
    int r15 = lane & 15;

    // A fragments hoisted, scaled by -2 (rank-key fusion), pinned
    short8v ah[4], am[4], al[4];
    #pragma unroll
    for (int t = 0; t < 4; ++t) {
        size_t ii = (size_t)(itile * IT + w * 64 + t * 16 + r15);
        ah[t] = scale_m2(*(const short8v*)(xhb + ii * 32 + g * 8));
        am[t] = scale_m2(*(const short8v*)(xmb + ii * 32 + g * 8));
        al[t] = scale_m2(*(const short8v*)(xlb + ii * 32 + g * 8));
    }
    #pragma unroll
    for (int t = 0; t < 4; ++t) {
        asm volatile("" : "+v"(ah[t]));
        asm volatile("" : "+v"(am[t]));
        asm volatile("" : "+v"(al[t]));
    }

    float bd[K]; int bi[K];                  // sorted ascending, registers
    #pragma unroll
    for (int r = 0; r < K; ++r) { bd[r] = 1e30f; bi[r] = 0; }
    float thr = 1e30f;
    int cnt = 0;

    auto flush = [&]() {
        int mc = cnt;                         // wave-max cnt (uniform loop bound)
        #pragma unroll
        for (int off = 1; off < 64; off <<= 1) {
            int o = __shfl_xor(mc, off);
            mc = mc > o ? mc : o;
        }
        #pragma unroll 1
        for (int u = 0; u < mc; ++u) {
            unsigned long long e = bufe[u * IT + tid];
            bool valid = u < cnt;
            float dd = valid ? __uint_as_float((unsigned int)(e >> 32)) : 1e30f;
            int ji = (int)(unsigned int)e;
            #pragma unroll
            for (int r = 0; r < K; ++r) {
                bool c = dd < bd[r];
                float tf = bd[r]; int ti = bi[r];
                bd[r] = c ? dd : bd[r]; bi[r] = c ? ji : bi[r];
                dd = c ? tf : dd;       ji = c ? ti : ji;
            }
        }
        cnt = 0; thr = bd[K - 1];
    };

#define LOADBS_(J, BH, BM, BL, SV)                                             \
    do {                                                                       \
        size_t ja_ = (size_t)(J) + r15;                                        \
        BH = *(const short8v*)(xhb + ja_ * 32 + g * 8);                        \
        BM = *(const short8v*)(xmb + ja_ * 32 + g * 8);                        \
        BL = *(const short8v*)(xlb + ja_ * 32 + g * 8);                        \
        SV = sqb[(size_t)(J) + r15];                                           \
    } while (0)

#define MFMA_(BH, BM, BL, SV)                                                  \
    do {                                                                       \
        _Pragma("unroll")                                                      \
        for (int t = 0; t < 4; ++t) {                                          \
            f32x4 acc = {SV, SV, SV, SV};                                      \
            acc = __builtin_amdgcn_mfma_f32_16x16x32_bf16(am[t], BM, acc, 0, 0, 0); \
            acc = __builtin_amdgcn_mfma_f32_16x16x32_bf16(ah[t], BL, acc, 0, 0, 0); \
            acc = __builtin_amdgcn_mfma_f32_16x16x32_bf16(al[t], BH, acc, 0, 0, 0); \
            acc = __builtin_amdgcn_mfma_f32_16x16x32_bf16(ah[t], BM, acc, 0, 0, 0); \
            acc = __builtin_amdgcn_mfma_f32_16x16x32_bf16(am[t], BH, acc, 0, 0, 0); \
            acc = __builtin_amdgcn_mfma_f32_16x16x32_bf16(ah[t], BH, acc, 0, 0, 0); \
            int il_ = w * 64 + t * 16 + g * 4;                                 \
            Dl[(il_ + 0) * DS + r15] = acc[0];                                 \
            Dl[(il_ + 1) * DS + r15] = acc[1];                                 \
            Dl[(il_ + 2) * DS + r15] = acc[2];                                 \
            Dl[(il_ + 3) * DS + r15] = acc[3];                                 \
        }                                                                      \
    } while (0)

#define PACK_(D, J) ((((unsigned long long)__float_as_uint(D)) << 32) | (unsigned int)(J))

#define SELECT_(J0)                                                            \
    do {                                                                       \
        _Pragma("unroll 1")                                                    \
        for (int jq = 0; jq < 16; jq += 4) {                                   \
            float d0 = Dl[tid * DS + jq + 0];                                  \
            float d1 = Dl[tid * DS + jq + 1];                                  \
            float d2 = Dl[tid * DS + jq + 2];                                  \
            float d3 = Dl[tid * DS + jq + 3];                                  \
            int j_ = (J0) + jq;                                                \
            if (d0 < thr) { bufe[cnt * IT + tid] = PACK_(d0, j_ + 0); cnt++; } \
            if (d1 < thr) { bufe[cnt * IT + tid] = PACK_(d1, j_ + 1); cnt++; } \
            if (d2 < thr) { bufe[cnt * IT + tid] = PACK_(d2, j_ + 2); cnt++; } \
            if (d3 < thr) { bufe[cnt * IT + tid] = PACK_(d3, j_ + 3); cnt++; } \
            if (__any(cnt >= C - 3)) flush();                                  \
        }                                                                      \
    } while (0)

    int jbase = jseg * JR;
    short8v bhA, bmA, blA, bhB, bmB, blB;
    float svA, svB;
    LOADBS_(jbase, bhA, bmA, blA, svA);      // prologue: B + sq for chunk 0
    #pragma unroll 1
    for (int ch = 0; ch < NCH; ch += 2) {
        int j0 = jbase + ch * 16;
        int j1 = j0 + 16;
        LOADBS_(j1, bhB, bmB, blB, svB);     // prefetch chunk ch+1
        MFMA_(bhA, bmA, blA, svA);
        SELECT_(j0);
        int j2 = (ch + 2 < NCH) ? j1 + 16 : jbase;   // clamp tail (harmless refetch)
        LOADBS_(j2, bhA, bmA, blA, svA);     // prefetch next pair
        MFMA_(bhB, bmB, blB, svB);
        SELECT_(j1);
    }
    flush();
#undef LOADBS_
#undef MFMA_
#undef PACK_
#undef SELECT_
    size_t base = ((size_t)jseg * (NB * NPTS) + (size_t)(b * NPTS) + itile * IT + tid) * K;
    #pragma unroll
    for (int r = 0; r < K; ++r) { cand_d[base + r] = bd[r]; cand_i[base + r] = bi[r]; }
}

// ---------------- merge v2: register insertion-chain with per-segment early exit ----------------
template <int K, int JS>
__global__ __launch_bounds__(128, 4) void k_knn_merge2(const float* __restrict__ cand_d,
                                                       const int* __restrict__ cand_i,
                                                       int* __restrict__ idx_out) {
    int p = blockIdx.x * 128 + threadIdx.x;   // over NB*NPTS
    float bd[K]; int bi[K];
    #pragma unroll
    for (int r = 0; r < K; ++r) { bd[r] = 1e30f; bi[r] = 0; }
    float thr = 1e30f;
    #pragma unroll 1
    for (int s = 0; s < JS; ++s) {
        size_t base = ((size_t)s * (NB * NPTS) + p) * K;
        #pragma unroll 1
        for (int r = 0; r < K; ++r) {
            float d = cand_d[base + r];
            if (!(d < thr)) break;            // sorted: rest of segment can't insert
            int j = cand_i[base + r];
            float dd = d; int ji = j;
            #pragma unroll
            for (int q = 0; q < K; ++q) {
                bool c = dd < bd[q];
                float tf = bd[q]; int ti = bi[q];
                bd[q] = c ? dd : bd[q]; bi[q] = c ? ji : bi[q];
                dd = c ? tf : dd;       ji = c ? ti : ji;
            }
            thr = bd[K - 1];
        }
    }
    int* op = idx_out + (size_t)p * K;
    #pragma unroll
    for (int r = 0; r < K; ++r) op[r] = bi[r];
}

// ---------------- EdgeConv v5: layer-2 on MFMA (fragment layouts proven in kNN) ----------------
// h1 = lrelu(A_j + Bm_i) built IN-REGISTER per lane (edge = lane&15, c-chunk =
// (lane>>4)*8 + kc*32 == exactly the lane's A-frag elements), split 2-term bf16.
// Wb pre-packed in B-frag order (hi/lo) -> LDS -> contiguous ds_read_b128.
// y = max over edges of lrelu(C + bb). K=12: pad to 16 edges by duplicating edge 0
// (max unchanged); rows live in regs (4) x quarters -> shfl_xor(16,32) reduce.
// K=4: 16-row tile = 4 points; quarter q holds point q's 4 edges as regs.
template <int K>
__global__ __launch_bounds__(128, 2)
void k_edgeconv5(const int* __restrict__ idx,
                 const float* __restrict__ A, const float* __restrict__ Bm,
                 const unsigned short* __restrict__ wpackL,   // layer base (2 levels)
                 const float* __restrict__ bb,
                 float* __restrict__ y) {
    __shared__ __align__(16) unsigned short Wfr[32768];   // hi[16384] | lo[16384]
    __shared__ float bb_s[128];

    int tid = threadIdx.x;
    {   // stage packed Wb (64 KB) + bb
        const uint4* src = (const uint4*)wpackL;
        uint4* dst = (uint4*)Wfr;
        #pragma unroll
        for (int i = 0; i < 32; ++i) dst[tid + i * 128] = src[tid + i * 128];
        if (tid < 128) bb_s[tid] = bb[tid];
    }
    __syncthreads();

    int lane = tid & 63;
    int wv = tid >> 6;
    int e = lane & 15;         // A-frag row
    int q = lane >> 4;         // quarter: A-frag k-chunk / C row group
    int b = blockIdx.x >> 8;   // batch
    const int* idxb = idx + ((size_t)b * NPTS) * K;
    const float4* A4 = (const float4*)(A + ((size_t)b * NPTS) * 128);
    const float4* B4 = (const float4*)(Bm + ((size_t)b * NPTS) * 128);
    float* yb = y + ((size_t)b * NPTS) * 128;

    float bbv[8];
    #pragma unroll
    for (int nt = 0; nt < 8; ++nt) bbv[nt] = bb_s[nt * 16 + e];

    constexpr int TILES = (K == 12) ? 16 : 4;   // per-wave work items
    int base0 = (blockIdx.x & 255) * ((K == 12) ? 32 : 32);  // 32 points per block

    #pragma unroll 1
    for (int ti = 0; ti < TILES; ++ti) {
        // resolve this lane's A-row -> (point, edge) and gather rows
        int prow, j;
        int ptile = 0;
        if constexpr (K == 12) {
            prow = base0 + wv * 16 + ti;                 // one point per tile
            int eidx = (e < 12) ? e : 0;                 // pad: duplicate edge 0
            j = idxb[prow * 12 + eidx];
        } else {
            ptile = (base0 >> 2) + wv * 4 + ti;          // tile of 4 points
            prow = ptile * 4 + (e >> 2);
            j = idxb[prow * 4 + (e & 3)];
        }
        // build A-frags: h1 = lrelu(A[j][c] + Bm[prow][c]), 2-term bf16 split
        short8v ahh[4], ahl[4];
        #pragma unroll
        for (int kc = 0; kc < 4; ++kc) {
            int c4off = kc * 8 + q * 2;
            float4 a0 = A4[(size_t)j * 32 + c4off];
            float4 a1 = A4[(size_t)j * 32 + c4off + 1];
            float4 b0 = B4[(size_t)prow * 32 + c4off];
            float4 b1 = B4[(size_t)prow * 32 + c4off + 1];
            float h[8];
            h[0] = lrelu(a0.x + b0.x); h[1] = lrelu(a0.y + b0.y);
            h[2] = lrelu(a0.z + b0.z); h[3] = lrelu(a0.w + b0.w);
            h[4] = lrelu(a1.x + b1.x); h[5] = lrelu(a1.y + b1.y);
            h[6] = lrelu(a1.z + b1.z); h[7] = lrelu(a1.w + b1.w);
            unsigned int wh[4], wl[4];
            #pragma unroll
            for (int i2 = 0; i2 < 4; ++i2) {
                unsigned short h0 = f2bf(h[2 * i2]);
                unsigned short h1b = f2bf(h[2 * i2 + 1]);
                unsigned short l0 = f2bf(h[2 * i2] - bf2f(h0));
                unsigned short l1 = f2bf(h[2 * i2 + 1] - bf2f(h1b));
                wh[i2] = (unsigned int)h0 | ((unsigned int)h1b << 16);
                wl[i2] = (unsigned int)l0 | ((unsigned int)l1 << 16);
            }
            uint4 uh = make_uint4(wh[0], wh[1], wh[2], wh[3]);
            uint4 ul = make_uint4(wl[0], wl[1], wl[2], wl[3]);
            ahh[kc] = *(short8v*)&uh;
            ahl[kc] = *(short8v*)&ul;
        }
        // GEMM: 8 n-tiles x 4 kc x 3 terms; 8 independent acc chains
        f32x4 acc[8];
        #pragma unroll
        for (int nt = 0; nt < 8; ++nt) {
            f32x4 ai = {bbv[nt], bbv[nt], bbv[nt], bbv[nt]};
            acc[nt] = ai;
        }
        #pragma unroll
        for (int kc = 0; kc < 4; ++kc) {
            #pragma unroll
            for (int nt = 0; nt < 8; ++nt) {
                short8v bh = *(const short8v*)&Wfr[(kc * 8 + nt) * 512 + lane * 8];
                short8v bl = *(const short8v*)&Wfr[16384 + (kc * 8 + nt) * 512 + lane * 8];
                acc[nt] = __builtin_amdgcn_mfma_f32_16x16x32_bf16(ahh[kc], bh, acc[nt], 0, 0, 0);
                acc[nt] = __builtin_amdgcn_mfma_f32_16x16x32_bf16(ahh[kc], bl, acc[nt], 0, 0, 0);
                acc[nt] = __builtin_amdgcn_mfma_f32_16x16x32_bf16(ahl[kc], bh, acc[nt], 0, 0, 0);
            }
        }
        // epilogue: lrelu + max over edges, write y
        #pragma unroll
        for (int nt = 0; nt < 8; ++nt) {
            float m = lrelu(acc[nt][0]);
            m = fmaxf(m, lrelu(acc[nt][1]));
            m = fmaxf(m, lrelu(acc[nt][2]));
            m = fmaxf(m, lrelu(acc[nt][3]));
            if constexpr (K == 12) {
                m = fmaxf(m, __shfl_xor(m, 16));
                m = fmaxf(m, __shfl_xor(m, 32));
                if (lane < 16) yb[(size_t)prow * 128 + nt * 16 + lane] = m;
            } else {
                // quarter q = point ptile*4+q; col = e
                yb[(size_t)(ptile * 4 + q) * 128 + nt * 16 + e] = m;
            }
        }
    }
}

// ---------------- conv_mid: y -> x1 fp32 + sq1 + bf16 h/m/l split ----------------
__global__ void k_conv_mid(const float* __restrict__ xin, const float* __restrict__ W,
                           const float* __restrict__ bias, float* __restrict__ out,
                           float* __restrict__ sq, unsigned short* __restrict__ xh,
                           unsigned short* __restrict__ xm, unsigned short* __restrict__ xl) {
    int gid = blockIdx.x * blockDim.x + threadIdx.x;
    const float4* row = (const float4*)(xin + (size_t)gid * 128);
    float acc[32];
    #pragma unroll
    for (int o = 0; o < 32; ++o) acc[o] = bias[o];
    #pragma unroll 2
    for (int c4 = 0; c4 < 32; ++c4) {
        float4 v = row[c4];
        #pragma unroll
        for (int o = 0; o < 32; ++o) {
            const float* w = W + o * 128 + c4 * 4;   // uniform -> s_load
            acc[o] += v.x * w[0] + v.y * w[1] + v.z * w[2] + v.w * w[3];
        }
    }
    float s = 0.f;
    float4* op = (float4*)(out + (size_t)gid * 32);
    unsigned int* hrow = (unsigned int*)(xh + (size_t)gid * 32);
    unsigned int* mrow = (unsigned int*)(xm + (size_t)gid * 32);
    unsigned int* lrow = (unsigned int*)(xl + (size_t)gid * 32);
    #pragma unroll
    for (int o4 = 0; o4 < 8; ++o4) {
        float4 v = make_float4(lrelu(acc[o4 * 4]), lrelu(acc[o4 * 4 + 1]),
                               lrelu(acc[o4 * 4 + 2]), lrelu(acc[o4 * 4 + 3]));
        s += v.x * v.x + v.y * v.y + v.z * v.z + v.w * v.w;
        op[o4] = v;
        unsigned int hp[2], mp[2], lp[2];
        split3(v, hp, mp, lp);
        *(uint2*)(hrow + o4 * 2) = make_uint2(hp[0], hp[1]);
        *(uint2*)(mrow + o4 * 2) = make_uint2(mp[0], mp[1]);
        *(uint2*)(lrow + o4 * 2) = make_uint2(lp[0], lp[1]);
    }
    sq[gid] = s;
}

// ---------------- decoder: y1 [B*N,128] -> out [B*N,12] ----------------
__global__ void k_decoder(const float* __restrict__ xin,
                          const float* __restrict__ W0, const float* __restrict__ b0,
                          const float* __restrict__ W1, const float* __restrict__ b1,
                          const float* __restrict__ W2, const float* __restrict__ b2,
                          float* __restrict__ out) {
    int gid = blockIdx.x * blockDim.x + threadIdx.x;
    const float4* row = (const float4*)(xin + (size_t)gid * 128);
    float h0[6];
    #pragma unroll
    for (int o = 0; o < 6; ++o) h0[o] = b0[o];
    #pragma unroll 4
    for (int c4 = 0; c4 < 32; ++c4) {
        float4 v = row[c4];
        #pragma unroll
        for (int o = 0; o < 6; ++o) {
            const float* w = W0 + o * 128 + c4 * 4;
            h0[o] += v.x * w[0] + v.y * w[1] + v.z * w[2] + v.w * w[3];
        }
    }
    #pragma unroll
    for (int o = 0; o < 6; ++o) h0[o] = lrelu(h0[o]);
    float h1[12];
    #pragma unroll
    for (int o = 0; o < 12; ++o) {
        float a = b1[o];
        #pragma unroll
        for (int j = 0; j < 6; ++j) a += W1[o * 6 + j] * h0[j];
        h1[o] = lrelu(a);
    }
    float* op = out + (size_t)gid * 12;
    #pragma unroll
    for (int o = 0; o < 12; ++o) {
        float a = b2[o];
        #pragma unroll
        for (int j = 0; j < 12; ++j) a += W2[o * 12 + j] * h1[j];
        op[o] = a;
    }
}

extern "C" void kernel_launch(void* const* d_in, const int* in_sizes, int n_in,
                              void* d_out, int out_size, void* d_ws, size_t ws_size,
                              hipStream_t stream) {
    const float* feature = (const float*)d_in[0];
    const float* Wc0 = (const float*)d_in[1];
    const float* bc0 = (const float*)d_in[2];
    const float* We0a = (const float*)d_in[3];
    const float* be0a = (const float*)d_in[4];
    const float* We0b = (const float*)d_in[5];
    const float* be0b = (const float*)d_in[6];
    const float* Wc1 = (const float*)d_in[7];
    const float* bc1 = (const float*)d_in[8];
    const float* We1a = (const float*)d_in[9];
    const float* be1a = (const float*)d_in[10];
    const float* We1b = (const float*)d_in[11];
    const float* be1b = (const float*)d_in[12];
    const float* Wd0 = (const float*)d_in[13];
    const float* bd0 = (const float*)d_in[14];
    const float* Wd1 = (const float*)d_in[15];
    const float* bd1 = (const float*)d_in[16];
    const float* Wd2 = (const float*)d_in[17];
    const float* bd2 = (const float*)d_in[18];
    float* out = (float*)d_out;

    float* f = (float*)d_ws;
    // layout (floats), total ~30.7 MB with phase-based aliasing (JS=16 variant)
    float* x0   = f;                       // [0, 524288)
    float* x1   = f + 524288;              // [524288, 1048576)
    int*   idx0 = (int*)(f + 1048576);     // 196608
    int*   idx1 = (int*)(f + 1245184);     // 65536
    unsigned short* wpack = (unsigned short*)(f + 1310720);  // 65536 shorts (32768 floats)
    float* Zab  = f + 1343488;             // 4194304: A | Bm
    float* Abuf = Zab;                     // 2097152
    float* Bbuf = Zab + 2097152;           // 2097152
    float* Y    = f + 5537792;             // 2097152: y0, later y1
    float* sq0  = f + 7634944;             // 16384
    float* sq1  = f + 7651328;             // 16384 (end 7667712)
    // kNN0 (JS=16, K=12): splits live in x1+idx slots (dead then); c0 spans Zab+Y
    unsigned short* xh0 = (unsigned short*)(f + 524288);    // 262144 floats (x1 lo)
    unsigned short* xm0 = (unsigned short*)(f + 786432);    // 262144 floats (x1 hi)
    unsigned short* xl0 = (unsigned short*)(f + 1048576);   // 262144 floats (idx0+idx1 slots)
    float* c0d  = f + 1343488;             // 3145728 (Zab + part of range)
    int*   c0i  = (int*)(f + 4489216);     // 3145728, ends 7634944 (rest of Zab + Y)
    // kNN1 (JS=16, K=4): splits + cands all inside Zab (Abuf/Bbuf from block0 dead)
    unsigned short* xh1 = (unsigned short*)Zab;             // 262144 floats
    unsigned short* xm1 = (unsigned short*)(Zab + 262144);
    unsigned short* xl1 = (unsigned short*)(Zab + 524288);
    float* c1d  = Zab + 786432;            // 1048576
    int*   c1i  = (int*)(Zab + 1835008);   // 1048576, ends Zab+2883584 < 4194304

    k_prepack_wb<<<128, 256, 0, stream>>>(We0b, We1b, wpack);
    k_conv_in<<<64, 256, 0, stream>>>(feature, Wc0, bc0, x0, sq0, xh0, xm0, xl0);
    k_knn_mfma<12, 16, 10><<<2048, 128, 0, stream>>>(xh0, xm0, xl0, sq0, c0d, c0i);
    k_knn_merge2<12, 16><<<128, 128, 0, stream>>>(c0d, c0i, idx0);
    k_premix<<<256, 256, 0, stream>>>(x0, We0a, be0a, Abuf, Bbuf);
    k_edgeconv5<12><<<512, 128, 0, stream>>>(idx0, Abuf, Bbuf, wpack, be0b, Y);
    k_conv_mid<<<64, 256, 0, stream>>>(Y, Wc1, bc1, x1, sq1, xh1, xm1, xl1);
    k_knn_mfma<4, 16, 8><<<2048, 128, 0, stream>>>(xh1, xm1, xl1, sq1, c1d, c1i);
    k_knn_merge2<4, 16><<<128, 128, 0, stream>>>(c1d, c1i, idx1);
    k_premix<<<256, 256, 0, stream>>>(x1, We1a, be1a, Abuf, Bbuf);
    k_edgeconv5<4><<<512, 128, 0, stream>>>(idx1, Abuf, Bbuf, wpack + 32768, be1b, Y);
    k_decoder<<<64, 256, 0, stream>>>(Y, Wd0, bd0, Wd1, bd1, Wd2, bd2, out);
}

// Round 29
// 578.843 us; speedup vs baseline: 1.0954x; 1.0090x over previous
//
#include <hip/hip_runtime.h>

#define NPTS 8192
#define NB 2

typedef __attribute__((ext_vector_type(8))) short short8v;   // 8 bf16 (4 VGPRs)
typedef __attribute__((ext_vector_type(4))) float f32x4;

__device__ __forceinline__ float lrelu(float x) { return x > 0.f ? x : 0.2f * x; }
__device__ __forceinline__ unsigned short f2bf(float f) {     // RNE bf16
    unsigned int u = __float_as_uint(f);
    return (unsigned short)((u + 0x7FFFu + ((u >> 16) & 1u)) >> 16);
}
__device__ __forceinline__ float bf2f(unsigned short h) {
    return __uint_as_float(((unsigned int)h) << 16);
}
// multiply 8 packed bf16 by -2: exponent+1 then sign flip (exact pow-2 scale)
__device__ __forceinline__ short8v scale_m2(short8v v) {
    uint4 u = *(uint4*)&v;
    u.x = (u.x + 0x00800080u) ^ 0x80008000u;
    u.y = (u.y + 0x00800080u) ^ 0x80008000u;
    u.z = (u.z + 0x00800080u) ^ 0x80008000u;
    u.w = (u.w + 0x00800080u) ^ 0x80008000u;
    return *(short8v*)&u;
}

// 3-way bf16 split of a float4, packed into 2 uints per level
__device__ __forceinline__ void split3(float4 v, unsigned int* hp, unsigned int* mp,
                                       unsigned int* lp) {
    float c[4] = {v.x, v.y, v.z, v.w};
    unsigned short h[4], m[4], l[4];
    #pragma unroll
    for (int i = 0; i < 4; ++i) {
        h[i] = f2bf(c[i]);
        float r1 = c[i] - bf2f(h[i]);
        m[i] = f2bf(r1);
        float r2 = r1 - bf2f(m[i]);
        l[i] = f2bf(r2);
    }
    hp[0] = (unsigned int)h[0] | ((unsigned int)h[1] << 16);
    hp[1] = (unsigned int)h[2] | ((unsigned int)h[3] << 16);
    mp[0] = (unsigned int)m[0] | ((unsigned int)m[1] << 16);
    mp[1] = (unsigned int)m[2] | ((unsigned int)m[3] << 16);
    lp[0] = (unsigned int)l[0] | ((unsigned int)l[1] << 16);
    lp[1] = (unsigned int)l[2] | ((unsigned int)l[3] << 16);
}

// ---------------- prepack Wb (both layers) into MFMA B-fragment order, bf16 hi/lo ----------------
__global__ void k_prepack_wb(const float* __restrict__ Wb0, const float* __restrict__ Wb1,
                             unsigned short* __restrict__ out) {
    int t = blockIdx.x * 256 + threadIdx.x;    // 32768 threads
    int L = t >> 14;
    int idx = t & 16383;
    int frag = idx >> 9;                        // kc*8 + nt
    int lane = (idx >> 3) & 63;
    int e = idx & 7;
    int kc = frag >> 3, nt = frag & 7;
    int k = kc * 32 + (lane >> 4) * 8 + e;
    int n = nt * 16 + (lane & 15);
    const float* Wb = L ? Wb1 : Wb0;
    float val = Wb[n * 128 + k];
    unsigned short hi = f2bf(val);
    unsigned short lo = f2bf(val - bf2f(hi));
    out[(L * 2 + 0) * 16384 + idx] = hi;
    out[(L * 2 + 1) * 16384 + idx] = lo;
}

// ---------------- conv_in: feature -> x0 fp32 + sq0 + bf16 h/m/l split ----------------
__global__ void k_conv_in(const float* __restrict__ f, const float* __restrict__ W,
                          const float* __restrict__ bias, float* __restrict__ out,
                          float* __restrict__ sq, unsigned short* __restrict__ xh,
                          unsigned short* __restrict__ xm, unsigned short* __restrict__ xl) {
    int gid = blockIdx.x * 64 + threadIdx.x;   // over B*N (256 blocks x 64)
    int b = gid >> 13, n = gid & (NPTS - 1);
    const float* fb = f + ((size_t)b << 20) + n;       // b*128*8192
    float acc[32];
    #pragma unroll
    for (int o = 0; o < 32; ++o) acc[o] = bias[o];
    #pragma unroll 4
    for (int c = 0; c < 128; ++c) {
        float xc = fb[(size_t)c * NPTS];               // coalesced across lanes
        #pragma unroll
        for (int o = 0; o < 32; ++o) acc[o] += xc * W[o * 128 + c];  // uniform -> s_load
    }
    float s = 0.f;
    float4* op = (float4*)(out + (size_t)gid * 32);
    unsigned int* hrow = (unsigned int*)(xh + (size_t)gid * 32);
    unsigned int* mrow = (unsigned int*)(xm + (size_t)gid * 32);
    unsigned int* lrow = (unsigned int*)(xl + (size_t)gid * 32);
    #pragma unroll
    for (int o4 = 0; o4 < 8; ++o4) {
        float4 v = make_float4(lrelu(acc[o4 * 4]), lrelu(acc[o4 * 4 + 1]),
                               lrelu(acc[o4 * 4 + 2]), lrelu(acc[o4 * 4 + 3]));
        s += v.x * v.x + v.y * v.y + v.z * v.z + v.w * v.w;
        op[o4] = v;
        unsigned int hp[2], mp[2], lp[2];
        split3(v, hp, mp, lp);
        *(uint2*)(hrow + o4 * 2) = make_uint2(hp[0], hp[1]);
        *(uint2*)(mrow + o4 * 2) = make_uint2(mp[0], mp[1]);
        *(uint2*)(lrow + o4 * 2) = make_uint2(lp[0], lp[1]);
    }
    sq[gid] = s;
}

// ---------------- premix: A = x @ Wa1^T ; Bm = x @ (Wa2-Wa1)^T + ba ----------------
__global__ __launch_bounds__(256, 2) void k_premix(const float* __restrict__ x,
                                                   const float* __restrict__ Wa,
                                                   const float* __restrict__ ba,
                                                   float* __restrict__ A,
                                                   float* __restrict__ Bm) {
    int tid = threadIdx.x;
    int q = tid >> 6;                       // quarter (wave-uniform)
    int p = blockIdx.x * 64 + (tid & 63);   // point over NB*NPTS
    float4 xv[8];
    {
        const float4* xr = (const float4*)(x + (size_t)p * 32);
        #pragma unroll
        for (int u = 0; u < 8; ++u) xv[u] = xr[u];
    }
    const float* W0 = Wa + q * 32 * 64;     // rows q*32..q*32+31
    float acc[32];
    #pragma unroll
    for (int o = 0; o < 32; ++o) acc[o] = 0.f;
    #pragma unroll 2
    for (int c4 = 0; c4 < 8; ++c4) {
        float4 v = xv[c4];
        #pragma unroll
        for (int o = 0; o < 32; ++o) {
            const float* w = W0 + o * 64 + c4 * 4;   // uniform -> s_load
            acc[o] += v.x * w[0] + v.y * w[1] + v.z * w[2] + v.w * w[3];
        }
    }
    {
        float4* op = (float4*)(A + (size_t)p * 128 + q * 32);
        #pragma unroll
        for (int o4 = 0; o4 < 8; ++o4)
            op[o4] = make_float4(acc[o4 * 4], acc[o4 * 4 + 1], acc[o4 * 4 + 2], acc[o4 * 4 + 3]);
    }
    #pragma unroll
    for (int o = 0; o < 32; ++o) acc[o] = ba[q * 32 + o];
    #pragma unroll 2
    for (int c4 = 0; c4 < 8; ++c4) {
        float4 v = xv[c4];
        #pragma unroll
        for (int o = 0; o < 32; ++o) {
            const float* w1 = W0 + o * 64 + c4 * 4;
            const float* w2 = w1 + 32;
            acc[o] += v.x * (w2[0] - w1[0]) + v.y * (w2[1] - w1[1]) +
                      v.z * (w2[2] - w1[2]) + v.w * (w2[3] - w1[3]);
        }
    }
    {
        float4* op = (float4*)(Bm + (size_t)p * 128 + q * 32);
        #pragma unroll
        for (int o4 = 0; o4 < 8; ++o4)
            op[o4] = make_float4(acc[o4 * 4], acc[o4 * 4 + 1], acc[o4 * 4 + 2], acc[o4 * 4 + 3]);
    }
}

// ---------------- kNN via MFMA Gram, rank key fused into MFMA ----------------
// DS=20: Dl writes 2-way (free), selection reads one aligned ds_read_b128 per 4 j.
template <int K, int JS, int C>
__global__ __launch_bounds__(128, 2) void k_knn_mfma(const unsigned short* __restrict__ xh,
                                                     const unsigned short* __restrict__ xm,
                                                     const unsigned short* __restrict__ xl,
                                                     const float* __restrict__ sqg,
                                                     float* __restrict__ cand_d,
                                                     int* __restrict__ cand_i) {
    constexpr int IT = 128;                  // i-tile
    constexpr int JR = NPTS / JS;            // 512 for JS=16
    constexpr int NCH = JR / 16;             // chunks of 16 j
    constexpr int BPB = (NPTS / IT) * JS;    // blocks per batch
    constexpr int DS = 20;                   // Dl row stride: 16B-aligned reads, 2-way writes

    __shared__ __align__(16) float Dl[IT * DS];
    __shared__ unsigned long long bufe[C * IT];   // packed (d<<32)|j, conflict-free cols

    int tid = threadIdx.x;
    int bid = blockIdx.x;
    int b = bid / BPB;
    int r0b = bid - b * BPB;
    int itile = r0b / JS;
    int jseg = r0b - itile * JS;

    const unsigned short* xhb = xh + ((size_t)b * NPTS) * 32;
    const unsigned short* xmb = xm + ((size_t)b * NPTS) * 32;
    const unsigned short* xlb = xl + ((size_t)b * NPTS) * 32;
    const float* sqb = sqg + (size_t)b * NPTS;

    int lane = tid & 63;
    int w = tid >> 6;          // wave 0..1 -> i rows [w*64, w*64+64)
    int g = lane >> 4;         // k-group: k = g*8 + e
    int r15 = lane & 15;

    // A fragments hoisted, scaled by -2 (rank-key fusion), pinned
    short8v ah[4], am[4], al[4];
    #pragma unroll
    for (int t = 0; t < 4; ++t) {
        size_t ii = (size_t)(itile * IT + w * 64 + t * 16 + r15);
        ah[t] = scale_m2(*(const short8v*)(xhb + ii * 32 + g * 8));
        am[t] = scale_m2(*(const short8v*)(xmb + ii * 32 + g * 8));
        al[t] = scale_m2(*(const short8v*)(xlb + ii * 32 + g * 8));
    }
    #pragma unroll
    for (int t = 0; t < 4; ++t) {
        asm volatile("" : "+v"(ah[t]));
        asm volatile("" : "+v"(am[t]));
        asm volatile("" : "+v"(al[t]));
    }

    float bd[K]; int bi[K];                  // sorted ascending, registers
    #pragma unroll
    for (int r = 0; r < K; ++r) { bd[r] = 1e30f; bi[r] = 0; }
    float thr = 1e30f;
    int cnt = 0;

    auto flush = [&]() {
        int mc = cnt;                         // wave-max cnt (uniform loop bound)
        #pragma unroll
        for (int off = 1; off < 64; off <<= 1) {
            int o = __shfl_xor(mc, off);
            mc = mc > o ? mc : o;
        }
        #pragma unroll 1
        for (int u = 0; u < mc; ++u) {
            unsigned long long e = bufe[u * IT + tid];
            bool valid = u < cnt;
            float dd = valid ? __uint_as_float((unsigned int)(e >> 32)) : 1e30f;
            int ji = (int)(unsigned int)e;
            #pragma unroll
            for (int r = 0; r < K; ++r) {
                bool c = dd < bd[r];
                float tf = bd[r]; int ti = bi[r];
                bd[r] = c ? dd : bd[r]; bi[r] = c ? ji : bi[r];
                dd = c ? tf : dd;       ji = c ? ti : ji;
            }
        }
        cnt = 0; thr = bd[K - 1];
    };

#define LOADBS_(J, BH, BM, BL, SV)                                             \
    do {                                                                       \
        size_t ja_ = (size_t)(J) + r15;                                        \
        BH = *(const short8v*)(xhb + ja_ * 32 + g * 8);                        \
        BM = *(const short8v*)(xmb + ja_ * 32 + g * 8);                        \
        BL = *(const short8v*)(xlb + ja_ * 32 + g * 8);                        \
        SV = sqb[(size_t)(J) + r15];                                           \
    } while (0)

#define MFMA_(BH, BM, BL, SV)                                                  \
    do {                                                                       \
        _Pragma("unroll")                                                      \
        for (int t = 0; t < 4; ++t) {                                          \
            f32x4 acc = {SV, SV, SV, SV};                                      \
            acc = __builtin_amdgcn_mfma_f32_16x16x32_bf16(am[t], BM, acc, 0, 0, 0); \
            acc = __builtin_amdgcn_mfma_f32_16x16x32_bf16(ah[t], BL, acc, 0, 0, 0); \
            acc = __builtin_amdgcn_mfma_f32_16x16x32_bf16(al[t], BH, acc, 0, 0, 0); \
            acc = __builtin_amdgcn_mfma_f32_16x16x32_bf16(ah[t], BM, acc, 0, 0, 0); \
            acc = __builtin_amdgcn_mfma_f32_16x16x32_bf16(am[t], BH, acc, 0, 0, 0); \
            acc = __builtin_amdgcn_mfma_f32_16x16x32_bf16(ah[t], BH, acc, 0, 0, 0); \
            int il_ = w * 64 + t * 16 + g * 4;                                 \
            Dl[(il_ + 0) * DS + r15] = acc[0];                                 \
            Dl[(il_ + 1) * DS + r15] = acc[1];                                 \
            Dl[(il_ + 2) * DS + r15] = acc[2];                                 \
            Dl[(il_ + 3) * DS + r15] = acc[3];                                 \
        }                                                                      \
    } while (0)

#define PACK_(D, J) ((((unsigned long long)__float_as_uint(D)) << 32) | (unsigned int)(J))

#define SELECT_(J0)                                                            \
    do {                                                                       \
        _Pragma("unroll 1")                                                    \
        for (int jq = 0; jq < 16; jq += 4) {                                   \
            float4 dv = *(const float4*)&Dl[tid * DS + jq];   /* ds_read_b128 */ \
            int j_ = (J0) + jq;                                                \
            if (dv.x < thr) { bufe[cnt * IT + tid] = PACK_(dv.x, j_ + 0); cnt++; } \
            if (dv.y < thr) { bufe[cnt * IT + tid] = PACK_(dv.y, j_ + 1); cnt++; } \
            if (dv.z < thr) { bufe[cnt * IT + tid] = PACK_(dv.z, j_ + 2); cnt++; } \
            if (dv.w < thr) { bufe[cnt * IT + tid] = PACK_(dv.w, j_ + 3); cnt++; } \
            if (__any(cnt >= C - 3)) flush();                                  \
        }                                                                      \
    } while (0)

    int jbase = jseg * JR;
    short8v bhA, bmA, blA, bhB, bmB, blB;
    float svA, svB;
    LOADBS_(jbase, bhA, bmA, blA, svA);      // prologue: B + sq for chunk 0
    #pragma unroll 1
    for (int ch = 0; ch < NCH; ch += 2) {
        int j0 = jbase + ch * 16;
        int j1 = j0 + 16;
        LOADBS_(j1, bhB, bmB, blB, svB);     // prefetch chunk ch+1
        MFMA_(bhA, bmA, blA, svA);
        SELECT_(j0);
        int j2 = (ch + 2 < NCH) ? j1 + 16 : jbase;   // clamp tail (harmless refetch)
        LOADBS_(j2, bhA, bmA, blA, svA);     // prefetch next pair
        MFMA_(bhB, bmB, blB, svB);
        SELECT_(j1);
    }
    flush();
#undef LOADBS_
#undef MFMA_
#undef PACK_
#undef SELECT_
    size_t base = ((size_t)jseg * (NB * NPTS) + (size_t)(b * NPTS) + itile * IT + tid) * K;
    #pragma unroll
    for (int r = 0; r < K; ++r) { cand_d[base + r] = bd[r]; cand_i[base + r] = bi[r]; }
}

// ---------------- merge v2: register insertion-chain with per-segment early exit ----------------
template <int K, int JS>
__global__ __launch_bounds__(128, 4) void k_knn_merge2(const float* __restrict__ cand_d,
                                                       const int* __restrict__ cand_i,
                                                       int* __restrict__ idx_out) {
    int p = blockIdx.x * 128 + threadIdx.x;   // over NB*NPTS
    float bd[K]; int bi[K];
    #pragma unroll
    for (int r = 0; r < K; ++r) { bd[r] = 1e30f; bi[r] = 0; }
    float thr = 1e30f;
    #pragma unroll 1
    for (int s = 0; s < JS; ++s) {
        size_t base = ((size_t)s * (NB * NPTS) + p) * K;
        #pragma unroll 1
        for (int r = 0; r < K; ++r) {
            float d = cand_d[base + r];
            if (!(d < thr)) break;            // sorted: rest of segment can't insert
            int j = cand_i[base + r];
            float dd = d; int ji = j;
            #pragma unroll
            for (int q = 0; q < K; ++q) {
                bool c = dd < bd[q];
                float tf = bd[q]; int ti = bi[q];
                bd[q] = c ? dd : bd[q]; bi[q] = c ? ji : bi[q];
                dd = c ? tf : dd;       ji = c ? ti : ji;
            }
            thr = bd[K - 1];
        }
    }
    int* op = idx_out + (size_t)p * K;
    #pragma unroll
    for (int r = 0; r < K; ++r) op[r] = bi[r];
}

// ---------------- EdgeConv v5: layer-2 on MFMA (RNE/RNE split — R28 trunc reverted) ----------------
template <int K>
__global__ __launch_bounds__(128, 2)
void k_edgeconv5(const int* __restrict__ idx,
                 const float* __restrict__ A, const float* __restrict__ Bm,
                 const unsigned short* __restrict__ wpackL,   // layer base (2 levels)
                 const float* __restrict__ bb,
                 float* __restrict__ y) {
    __shared__ __align__(16) unsigned short Wfr[32768];   // hi[16384] | lo[16384]
    __shared__ float bb_s[128];

    int tid = threadIdx.x;
    {   // stage packed Wb (64 KB) + bb
        const uint4* src = (const uint4*)wpackL;
        uint4* dst = (uint4*)Wfr;
        #pragma unroll
        for (int i = 0; i < 32; ++i) dst[tid + i * 128] = src[tid + i * 128];
        if (tid < 128) bb_s[tid] = bb[tid];
    }
    __syncthreads();

    int lane = tid & 63;
    int wv = tid >> 6;
    int e = lane & 15;         // A-frag row
    int q = lane >> 4;         // quarter: A-frag k-chunk / C row group
    int b = blockIdx.x >> 8;   // batch
    const int* idxb = idx + ((size_t)b * NPTS) * K;
    const float4* A4 = (const float4*)(A + ((size_t)b * NPTS) * 128);
    const float4* B4 = (const float4*)(Bm + ((size_t)b * NPTS) * 128);
    float* yb = y + ((size_t)b * NPTS) * 128;

    float bbv[8];
    #pragma unroll
    for (int nt = 0; nt < 8; ++nt) bbv[nt] = bb_s[nt * 16 + e];

    constexpr int TILES = (K == 12) ? 16 : 4;   // per-wave work items
    int base0 = (blockIdx.x & 255) * 32;        // 32 points per block

    #pragma unroll 1
    for (int ti = 0; ti < TILES; ++ti) {
        int prow, j;
        int ptile = 0;
        if constexpr (K == 12) {
            prow = base0 + wv * 16 + ti;                 // one point per tile
            int eidx = (e < 12) ? e : 0;                 // pad: duplicate edge 0
            j = idxb[prow * 12 + eidx];
        } else {
            ptile = (base0 >> 2) + wv * 4 + ti;          // tile of 4 points
            prow = ptile * 4 + (e >> 2);
            j = idxb[prow * 4 + (e & 3)];
        }
        // build A-frags: h1 = lrelu(A[j][c] + Bm[prow][c]), RNE hi + RNE lo split
        short8v ahh[4], ahl[4];
        #pragma unroll
        for (int kc = 0; kc < 4; ++kc) {
            int c4off = kc * 8 + q * 2;
            float4 a0 = A4[(size_t)j * 32 + c4off];
            float4 a1 = A4[(size_t)j * 32 + c4off + 1];
            float4 b0 = B4[(size_t)prow * 32 + c4off];
            float4 b1 = B4[(size_t)prow * 32 + c4off + 1];
            float h[8];
            h[0] = lrelu(a0.x + b0.x); h[1] = lrelu(a0.y + b0.y);
            h[2] = lrelu(a0.z + b0.z); h[3] = lrelu(a0.w + b0.w);
            h[4] = lrelu(a1.x + b1.x); h[5] = lrelu(a1.y + b1.y);
            h[6] = lrelu(a1.z + b1.z); h[7] = lrelu(a1.w + b1.w);
            unsigned int wh[4], wl[4];
            #pragma unroll
            for (int i2 = 0; i2 < 4; ++i2) {
                unsigned short h0 = f2bf(h[2 * i2]);
                unsigned short h1b = f2bf(h[2 * i2 + 1]);
                unsigned short l0 = f2bf(h[2 * i2] - bf2f(h0));
                unsigned short l1 = f2bf(h[2 * i2 + 1] - bf2f(h1b));
                wh[i2] = (unsigned int)h0 | ((unsigned int)h1b << 16);
                wl[i2] = (unsigned int)l0 | ((unsigned int)l1 << 16);
            }
            uint4 uh = make_uint4(wh[0], wh[1], wh[2], wh[3]);
            uint4 ul = make_uint4(wl[0], wl[1], wl[2], wl[3]);
            ahh[kc] = *(short8v*)&uh;
            ahl[kc] = *(short8v*)&ul;
        }
        // GEMM: 8 n-tiles x 4 kc x 3 terms; 8 independent acc chains
        f32x4 acc[8];
        #pragma unroll
        for (int nt = 0; nt < 8; ++nt) {
            f32x4 ai = {bbv[nt], bbv[nt], bbv[nt], bbv[nt]};
            acc[nt] = ai;
        }
        #pragma unroll
        for (int kc = 0; kc < 4; ++kc) {
            #pragma unroll
            for (int nt = 0; nt < 8; ++nt) {
                short8v bh = *(const short8v*)&Wfr[(kc * 8 + nt) * 512 + lane * 8];
                short8v bl = *(const short8v*)&Wfr[16384 + (kc * 8 + nt) * 512 + lane * 8];
                acc[nt] = __builtin_amdgcn_mfma_f32_16x16x32_bf16(ahh[kc], bh, acc[nt], 0, 0, 0);
                acc[nt] = __builtin_amdgcn_mfma_f32_16x16x32_bf16(ahh[kc], bl, acc[nt], 0, 0, 0);
                acc[nt] = __builtin_amdgcn_mfma_f32_16x16x32_bf16(ahl[kc], bh, acc[nt], 0, 0, 0);
            }
        }
        // epilogue: lrelu + max over edges, write y
        #pragma unroll
        for (int nt = 0; nt < 8; ++nt) {
            float m = lrelu(acc[nt][0]);
            m = fmaxf(m, lrelu(acc[nt][1]));
            m = fmaxf(m, lrelu(acc[nt][2]));
            m = fmaxf(m, lrelu(acc[nt][3]));
            if constexpr (K == 12) {
                m = fmaxf(m, __shfl_xor(m, 16));
                m = fmaxf(m, __shfl_xor(m, 32));
                if (lane < 16) yb[(size_t)prow * 128 + nt * 16 + lane] = m;
            } else {
                yb[(size_t)(ptile * 4 + q) * 128 + nt * 16 + e] = m;
            }
        }
    }
}

// ---------------- conv_mid: y -> x1 fp32 + sq1 + bf16 h/m/l split (256x64 grid) ----------------
__global__ void k_conv_mid(const float* __restrict__ xin, const float* __restrict__ W,
                           const float* __restrict__ bias, float* __restrict__ out,
                           float* __restrict__ sq, unsigned short* __restrict__ xh,
                           unsigned short* __restrict__ xm, unsigned short* __restrict__ xl) {
    int gid = blockIdx.x * 64 + threadIdx.x;
    const float4* row = (const float4*)(xin + (size_t)gid * 128);
    float acc[32];
    #pragma unroll
    for (int o = 0; o < 32; ++o) acc[o] = bias[o];
    #pragma unroll 2
    for (int c4 = 0; c4 < 32; ++c4) {
        float4 v = row[c4];
        #pragma unroll
        for (int o = 0; o < 32; ++o) {
            const float* w = W + o * 128 + c4 * 4;   // uniform -> s_load
            acc[o] += v.x * w[0] + v.y * w[1] + v.z * w[2] + v.w * w[3];
        }
    }
    float s = 0.f;
    float4* op = (float4*)(out + (size_t)gid * 32);
    unsigned int* hrow = (unsigned int*)(xh + (size_t)gid * 32);
    unsigned int* mrow = (unsigned int*)(xm + (size_t)gid * 32);
    unsigned int* lrow = (unsigned int*)(xl + (size_t)gid * 32);
    #pragma unroll
    for (int o4 = 0; o4 < 8; ++o4) {
        float4 v = make_float4(lrelu(acc[o4 * 4]), lrelu(acc[o4 * 4 + 1]),
                               lrelu(acc[o4 * 4 + 2]), lrelu(acc[o4 * 4 + 3]));
        s += v.x * v.x + v.y * v.y + v.z * v.z + v.w * v.w;
        op[o4] = v;
        unsigned int hp[2], mp[2], lp[2];
        split3(v, hp, mp, lp);
        *(uint2*)(hrow + o4 * 2) = make_uint2(hp[0], hp[1]);
        *(uint2*)(mrow + o4 * 2) = make_uint2(mp[0], mp[1]);
        *(uint2*)(lrow + o4 * 2) = make_uint2(lp[0], lp[1]);
    }
    sq[gid] = s;
}

// ---------------- decoder: y1 [B*N,128] -> out [B*N,12] (256x64 grid) ----------------
__global__ void k_decoder(const float* __restrict__ xin,
                          const float* __restrict__ W0, const float* __restrict__ b0,
                          const float* __restrict__ W1, const float* __restrict__ b1,
                          const float* __restrict__ W2, const float* __restrict__ b2,
                          float* __restrict__ out) {
    int gid = blockIdx.x * 64 + threadIdx.x;
    const float4* row = (const float4*)(xin + (size_t)gid * 128);
    float h0[6];
    #pragma unroll
    for (int o = 0; o < 6; ++o) h0[o] = b0[o];
    #pragma unroll 4
    for (int c4 = 0; c4 < 32; ++c4) {
        float4 v = row[c4];
        #pragma unroll
        for (int o = 0; o < 6; ++o) {
            const float* w = W0 + o * 128 + c4 * 4;
            h0[o] += v.x * w[0] + v.y * w[1] + v.z * w[2] + v.w * w[3];
        }
    }
    #pragma unroll
    for (int o = 0; o < 6; ++o) h0[o] = lrelu(h0[o]);
    float h1[12];
    #pragma unroll
    for (int o = 0; o < 12; ++o) {
        float a = b1[o];
        #pragma unroll
        for (int j = 0; j < 6; ++j) a += W1[o * 6 + j] * h0[j];
        h1[o] = lrelu(a);
    }
    float* op = out + (size_t)gid * 12;
    #pragma unroll
    for (int o = 0; o < 12; ++o) {
        float a = b2[o];
        #pragma unroll
        for (int j = 0; j < 12; ++j) a += W2[o * 12 + j] * h1[j];
        op[o] = a;
    }
}

extern "C" void kernel_launch(void* const* d_in, const int* in_sizes, int n_in,
                              void* d_out, int out_size, void* d_ws, size_t ws_size,
                              hipStream_t stream) {
    const float* feature = (const float*)d_in[0];
    const float* Wc0 = (const float*)d_in[1];
    const float* bc0 = (const float*)d_in[2];
    const float* We0a = (const float*)d_in[3];
    const float* be0a = (const float*)d_in[4];
    const float* We0b = (const float*)d_in[5];
    const float* be0b = (const float*)d_in[6];
    const float* Wc1 = (const float*)d_in[7];
    const float* bc1 = (const float*)d_in[8];
    const float* We1a = (const float*)d_in[9];
    const float* be1a = (const float*)d_in[10];
    const float* We1b = (const float*)d_in[11];
    const float* be1b = (const float*)d_in[12];
    const float* Wd0 = (const float*)d_in[13];
    const float* bd0 = (const float*)d_in[14];
    const float* Wd1 = (const float*)d_in[15];
    const float* bd1 = (const float*)d_in[16];
    const float* Wd2 = (const float*)d_in[17];
    const float* bd2 = (const float*)d_in[18];
    float* out = (float*)d_out;

    float* f = (float*)d_ws;
    // layout (floats), total ~30.7 MB with phase-based aliasing (JS=16 variant)
    float* x0   = f;                       // [0, 524288)
    float* x1   = f + 524288;              // [524288, 1048576)
    int*   idx0 = (int*)(f + 1048576);     // 196608
    int*   idx1 = (int*)(f + 1245184);     // 65536
    unsigned short* wpack = (unsigned short*)(f + 1310720);  // 65536 shorts (32768 floats)
    float* Zab  = f + 1343488;             // 4194304: A | Bm
    float* Abuf = Zab;                     // 2097152
    float* Bbuf = Zab + 2097152;           // 2097152
    float* Y    = f + 5537792;             // 2097152: y0, later y1
    float* sq0  = f + 7634944;             // 16384
    float* sq1  = f + 7651328;             // 16384 (end 7667712)
    // kNN0 (JS=16, K=12): splits live in x1+idx slots (dead then); c0 spans Zab+Y
    unsigned short* xh0 = (unsigned short*)(f + 524288);    // 262144 floats (x1 lo)
    unsigned short* xm0 = (unsigned short*)(f + 786432);    // 262144 floats (x1 hi)
    unsigned short* xl0 = (unsigned short*)(f + 1048576);   // 262144 floats (idx0+idx1 slots)
    float* c0d  = f + 1343488;             // 3145728 (Zab + part of range)
    int*   c0i  = (int*)(f + 4489216);     // 3145728, ends 7634944 (rest of Zab + Y)
    // kNN1 (JS=16, K=4): splits + cands all inside Zab (Abuf/Bbuf from block0 dead)
    unsigned short* xh1 = (unsigned short*)Zab;             // 262144 floats
    unsigned short* xm1 = (unsigned short*)(Zab + 262144);
    unsigned short* xl1 = (unsigned short*)(Zab + 524288);
    float* c1d  = Zab + 786432;            // 1048576
    int*   c1i  = (int*)(Zab + 1835008);   // 1048576, ends Zab+2883584 < 4194304

    k_prepack_wb<<<128, 256, 0, stream>>>(We0b, We1b, wpack);
    k_conv_in<<<256, 64, 0, stream>>>(feature, Wc0, bc0, x0, sq0, xh0, xm0, xl0);
    k_knn_mfma<12, 16, 9><<<2048, 128, 0, stream>>>(xh0, xm0, xl0, sq0, c0d, c0i);
    k_knn_merge2<12, 16><<<128, 128, 0, stream>>>(c0d, c0i, idx0);
    k_premix<<<256, 256, 0, stream>>>(x0, We0a, be0a, Abuf, Bbuf);
    k_edgeconv5<12><<<512, 128, 0, stream>>>(idx0, Abuf, Bbuf, wpack, be0b, Y);
    k_conv_mid<<<256, 64, 0, stream>>>(Y, Wc1, bc1, x1, sq1, xh1, xm1, xl1);
    k_knn_mfma<4, 16, 8><<<2048, 128, 0, stream>>>(xh1, xm1, xl1, sq1, c1d, c1i);
    k_knn_merge2<4, 16><<<128, 128, 0, stream>>>(c1d, c1i, idx1);
    k_premix<<<256, 256, 0, stream>>>(x1, We1a, be1a, Abuf, Bbuf);
    k_edgeconv5<4><<<512, 128, 0, stream>>>(idx1, Abuf, Bbuf, wpack + 32768, be1b, Y);
    k_decoder<<<256, 64, 0, stream>>>(Y, Wd0, bd0, Wd1, bd1, Wd2, bd2, out);
}